// Round 8
// baseline (590.788 us; speedup 1.0000x reference)
//
#include <hip/hip_runtime.h>
#include <hip/hip_bf16.h>

#define C_DIM 128
#define EPS_LN 1e-5f

typedef short bf16x8 __attribute__((ext_vector_type(8)));
typedef float f32x4  __attribute__((ext_vector_type(4)));
typedef __hip_bfloat16 bf16;

__device__ inline unsigned short f2bu(float f) {
    bf16 h = __float2bfloat16(f);
    return *reinterpret_cast<unsigned short*>(&h);
}
__device__ inline float blo(unsigned int u) { return __uint_as_float(u << 16); }
__device__ inline float bhi(unsigned int u) { return __uint_as_float(u & 0xffff0000u); }
__device__ inline ushort4 pack4(float a, float b, float c, float d) {
    ushort4 r; r.x = f2bu(a); r.y = f2bu(b); r.z = f2bu(c); r.w = f2bu(d); return r;
}

// async global->LDS DMA, 16B per lane. LDS dest is WAVE-UNIFORM base;
// HW writes lane l's 16B at base + l*16. Global src is per-lane.
__device__ inline void async_copy16(const bf16* g, bf16* s) {
    __builtin_amdgcn_global_load_lds(
        (const __attribute__((address_space(1))) unsigned int*)g,
        (__attribute__((address_space(3))) unsigned int*)s,
        16, 0, 0);
}

// ---------------- weights convert+transpose + bias pack, ONE dispatch ------
// dst (bf16): Wqt|Wkt|Wvt|Wot (4x 128*128) | Wt1[512][128] | Wt2[128][512]
// then packed fp32 bqkv[384] right after.
__global__ __launch_bounds__(256) void wconv_all(
    const float* __restrict__ Wq, const float* __restrict__ Wk,
    const float* __restrict__ Wv, const float* __restrict__ Wo,
    const float* __restrict__ W1, const float* __restrict__ W2,
    const float* __restrict__ bq, const float* __restrict__ bk,
    const float* __restrict__ bv, bf16* __restrict__ dst) {
    int idx = blockIdx.x * 256 + threadIdx.x;
    if (idx < 65536) {                       // four 128x128 weights
        int r = idx >> 14, o = idx & 16383;
        int k = o >> 7, nn = o & 127;
        const float* W = (r == 0) ? Wq : (r == 1) ? Wk : (r == 2) ? Wv : Wo;
        dst[(r << 14) + nn * 128 + k] = __float2bfloat16(W[o]);
    } else if (idx < 131072) {               // W1 [128,512] -> Wt1[n][k]
        int o = idx - 65536;
        int k = o >> 9, nn = o & 511;
        dst[65536 + nn * 128 + k] = __float2bfloat16(W1[o]);
    } else if (idx < 196608) {               // W2 [512,128] -> Wt2[n][k]
        int o = idx - 131072;
        int k = o >> 7, nn = o & 127;
        dst[131072 + nn * 512 + k] = __float2bfloat16(W2[o]);
    } else if (idx < 196992) {               // packed bqkv[384] fp32
        int j = idx - 196608;
        int grp = j >> 7, col = j & 127;
        const float* bp = (grp == 0) ? bq : (grp == 1) ? bk : bv;
        ((float*)(dst + 196608))[j] = bp[col];
    }
}

__global__ __launch_bounds__(256) void zeroi_kernel(int* __restrict__ p, int n) {
    int i = blockIdx.x * 256 + threadIdx.x;
    if (i < n) p[i] = 0;
}

// ---------------- LayerNorm fp32 -> bf16, one wave per row -----------------
__global__ __launch_bounds__(256) void ln_kernel(
    const float* __restrict__ x, const float* __restrict__ g,
    const float* __restrict__ b, bf16* __restrict__ out, int n) {
    int wave = threadIdx.x >> 6;
    int lane = threadIdx.x & 63;
    int row = blockIdx.x * 4 + wave;
    if (row >= n) return;
    float2 v = ((const float2*)(x + (size_t)row * C_DIM))[lane];
    float s  = v.x + v.y;
    float ss = v.x * v.x + v.y * v.y;
    #pragma unroll
    for (int o = 1; o < 64; o <<= 1) {
        s  += __shfl_xor(s, o);
        ss += __shfl_xor(ss, o);
    }
    float mu  = s * (1.0f / C_DIM);
    float var = ss * (1.0f / C_DIM) - mu * mu;
    float rs  = rsqrtf(var + EPS_LN);
    float2 gg = ((const float2*)g)[lane];
    float2 bb = ((const float2*)b)[lane];
    __hip_bfloat162 o2;
    o2.x = __float2bfloat16((v.x - mu) * rs * gg.x + bb.x);
    o2.y = __float2bfloat16((v.y - mu) * rs * gg.y + bb.y);
    ((__hip_bfloat162*)(out + (size_t)row * C_DIM))[lane] = o2;
}

// ---------------- MFMA GEMM: A LDS-staged (DMA+swizzle), B direct L2 -------
// Block: 128 rows x 128 cols of C; 4 waves, each 32 rows x 128 cols.
// A [M,lda] bf16 row-major; Bt [Ncols][Kfull] bf16 (row = output col).
// Cost model (r7 lesson): GEMM time ~ bytes staged through the DMA+barrier
// path at fixed block-parallelism (~3.8 TB/s chip-wide), NOT HBM bytes.
// B = weights (96-128 KB, L2-resident, read by every block) -> read frags
// DIRECTLY global->VGPR (16B/lane L2 hits, compiler-pipelined); keep the
// streaming A on the 1KB-contiguous DMA path (r3 lesson: A-direct
// over-fetches HBM). LDS 64->32 KB; 3 blocks/CU via launch_bounds to hide
// ~200cy B-load latency. Numerics bitwise identical to DMA-both version.
// Tail: clamp A source row to M-1 (garbage masked in epilogue).
// Operand-swapped mfma(bf, af, acc): lane(m,q) reg r = C[row0+..+m][ct*16+q*4+r].
template<bool OUTBF16, bool RELU, bool FUSE_LN, int KSTEPS>
__global__ __launch_bounds__(256, 3) void gemm_lds(
    const bf16* __restrict__ A, int lda,
    const bf16* __restrict__ Bt, int Kfull,
    const float* __restrict__ biasBase,
    void* __restrict__ Cd, int ldc, size_t obStride,
    const float* __restrict__ resid, int ldres,
    int M,
    const float* __restrict__ g, const float* __restrict__ be,
    bf16* __restrict__ h2) {
    __shared__ bf16 As[128][128];
    int tid  = threadIdx.x;
    int lane = tid & 63;
    int w    = tid >> 6;
    int m = lane & 15, q = lane >> 4;
    int row0 = blockIdx.x * 128;
    const bf16* Bbase = Bt + (size_t)blockIdx.y * 128 * Kfull;
    // per-lane base for B fragment rows: row ct*16+m, col q*8
    const bf16* Bl = Bbase + (size_t)m * Kfull + q * 8;

    f32x4 acc[2][8];
    #pragma unroll
    for (int rt = 0; rt < 2; rt++)
        #pragma unroll
        for (int ct = 0; ct < 8; ct++) acc[rt][ct] = (f32x4){0.f, 0.f, 0.f, 0.f};

    int rsub  = lane >> 4;      // 0..3: this lane's dest row within a 4-row DMA call
    int cslot = lane & 15;      // this lane's 16B slot within the row

    for (int kt = 0; kt < KSTEPS; kt++) {
        // stage A tile [128][128] via 8 async DMA calls per wave
        #pragma unroll
        for (int i = 0; i < 8; i++) {
            int arow = w * 32 + i * 4 + rsub;                 // dest row 0..127
            int scol = (cslot ^ (arow & 7)) << 3;             // swizzled src slot (elems)
            int garow = row0 + arow;
            if (garow > M - 1) garow = M - 1;                 // tail clamp
            async_copy16(A + (size_t)garow * lda + kt * 128 + scol, &As[w * 32 + i * 4][0]);
        }
        __syncthreads();
        #pragma unroll
        for (int ks = 0; ks < 4; ks++) {
            int sofs = ((ks * 4 + q) ^ (m & 7)) << 3;         // swizzled read offset
            bf16x8 af0 = *(const bf16x8*)&As[w * 32 + m][sofs];
            bf16x8 af1 = *(const bf16x8*)&As[w * 32 + 16 + m][sofs];
            #pragma unroll
            for (int ct = 0; ct < 8; ct++) {
                // B fragment direct from global (L2-resident weights)
                bf16x8 bf = *(const bf16x8*)(Bl + (size_t)ct * 16 * Kfull + kt * 128 + ks * 32);
                acc[0][ct] = __builtin_amdgcn_mfma_f32_16x16x32_bf16(bf, af0, acc[0][ct], 0, 0, 0);
                acc[1][ct] = __builtin_amdgcn_mfma_f32_16x16x32_bf16(bf, af1, acc[1][ct], 0, 0, 0);
            }
        }
        if (kt + 1 < KSTEPS) __syncthreads();
    }

    // ---- epilogue ----
    #pragma unroll
    for (int rt = 0; rt < 2; rt++) {
        int row = row0 + w * 32 + rt * 16 + m;
        bool valid = row < M;
        float vals[8][4];
        #pragma unroll
        for (int ct = 0; ct < 8; ct++) {
            int col = ct * 16 + q * 4;
            float4 bv = make_float4(0.f, 0.f, 0.f, 0.f);
            if (biasBase) bv = *(const float4*)(biasBase + blockIdx.y * 128 + col);
            float4 rv = make_float4(0.f, 0.f, 0.f, 0.f);
            if (resid && valid) rv = *(const float4*)(resid + (size_t)row * ldres + col);
            vals[ct][0] = acc[rt][ct][0] + bv.x + rv.x;
            vals[ct][1] = acc[rt][ct][1] + bv.y + rv.y;
            vals[ct][2] = acc[rt][ct][2] + bv.z + rv.z;
            vals[ct][3] = acc[rt][ct][3] + bv.w + rv.w;
        }
        if (FUSE_LN) {
            // row spans lanes {m, m+16, m+32, m+48}: reduce over q via xor 16,32
            float s1 = 0.f, s2 = 0.f;
            #pragma unroll
            for (int ct = 0; ct < 8; ct++)
                #pragma unroll
                for (int r = 0; r < 4; r++) { s1 += vals[ct][r]; s2 += vals[ct][r] * vals[ct][r]; }
            s1 += __shfl_xor(s1, 16); s1 += __shfl_xor(s1, 32);
            s2 += __shfl_xor(s2, 16); s2 += __shfl_xor(s2, 32);
            float mu  = s1 * (1.0f / 128.f);
            float var = s2 * (1.0f / 128.f) - mu * mu;
            float rs  = rsqrtf(var + EPS_LN);
            if (valid) {
                #pragma unroll
                for (int ct = 0; ct < 8; ct++) {
                    int col = ct * 16 + q * 4;
                    *(float4*)((float*)Cd + (size_t)row * ldc + col) =
                        make_float4(vals[ct][0], vals[ct][1], vals[ct][2], vals[ct][3]);
                    float4 gg = *(const float4*)(g + col);
                    float4 bb = *(const float4*)(be + col);
                    *(ushort4*)(h2 + (size_t)row * 128 + col) =
                        pack4((vals[ct][0] - mu) * rs * gg.x + bb.x,
                              (vals[ct][1] - mu) * rs * gg.y + bb.y,
                              (vals[ct][2] - mu) * rs * gg.z + bb.z,
                              (vals[ct][3] - mu) * rs * gg.w + bb.w);
                }
            }
        } else if (valid) {
            #pragma unroll
            for (int ct = 0; ct < 8; ct++) {
                int col = ct * 16 + q * 4;
                float v0 = vals[ct][0], v1 = vals[ct][1];
                float v2 = vals[ct][2], v3 = vals[ct][3];
                if (RELU) {
                    v0 = fmaxf(v0, 0.f); v1 = fmaxf(v1, 0.f);
                    v2 = fmaxf(v2, 0.f); v3 = fmaxf(v3, 0.f);
                }
                if (OUTBF16) {
                    *(ushort4*)((bf16*)Cd + blockIdx.y * obStride + (size_t)row * ldc + col) =
                        pack4(v0, v1, v2, v3);
                } else {
                    *(float4*)((float*)Cd + blockIdx.y * obStride + (size_t)row * ldc + col) =
                        make_float4(v0, v1, v2, v3);
                }
            }
        }
    }
}

// ---------------- CSR build ------------------------------------------------
__global__ __launch_bounds__(256) void hist_kernel(
    const int* __restrict__ eidx, int* __restrict__ deg, int E_) {
    int e = blockIdx.x * 256 + threadIdx.x;
    if (e >= E_) return;
    atomicAdd(&deg[eidx[E_ + e]], 1);
}

__global__ __launch_bounds__(256) void alloc_kernel(
    const int* __restrict__ deg, int* __restrict__ start,
    int* __restrict__ cursor, int* __restrict__ counter, int n) {
    int i = blockIdx.x * 256 + threadIdx.x;
    if (i >= n) return;
    int d = deg[i];
    int s = atomicAdd(counter, d);
    start[i] = s;
    cursor[i] = s;
}

__global__ __launch_bounds__(256) void scatter_kernel(
    const int* __restrict__ eidx, int* __restrict__ cursor,
    int* __restrict__ esrc, int E_) {
    int e = blockIdx.x * 256 + threadIdx.x;
    if (e >= E_) return;
    int src = eidx[e];
    int dst = eidx[E_ + e];
    int pos = atomicAdd(&cursor[dst], 1);
    esrc[pos] = src;
}

// ---------- fused attention + aggregation: one wave per node ---------------
// (round-6 state: K + all-8-V loads issued together -> one exposed gather
// round; predicated phase 2, no branches; exp2f folded scale; fast div.)
__device__ inline float dot8f(uint4 a, uint4 b) {
    return blo(a.x) * blo(b.x) + bhi(a.x) * bhi(b.x)
         + blo(a.y) * blo(b.y) + bhi(a.y) * bhi(b.y)
         + blo(a.z) * blo(b.z) + bhi(a.z) * bhi(b.z)
         + blo(a.w) * blo(b.w) + bhi(a.w) * bhi(b.w);
}

__global__ __launch_bounds__(256) void attn_aggr_kernel(
    const bf16* __restrict__ Q, const bf16* __restrict__ K,
    const bf16* __restrict__ V,
    const int* __restrict__ start, const int* __restrict__ deg,
    const int* __restrict__ esrc, bf16* __restrict__ ag, int n) {
    int wave = threadIdx.x >> 6;
    int lane = threadIdx.x & 63;
    int i = blockIdx.x * 4 + wave;
    if (i >= n) return;
    int s = start[i], d = deg[i];
    int end = s + d;
    int g = lane >> 3;          // edge slot within 8-batch (== head in phase 2)
    int l = lane & 7;           // head owned in phase 1
    const uint4* qh = (const uint4*)(Q + (size_t)i * 128 + l * 16);
    uint4 q0 = qh[0], q1 = qh[1];
    const float SC = 0.25f * 1.44269504089f;   // /sqrt(16) * log2(e)
    float ax = 0.f, ay = 0.f;
    for (int j = s; j < end; j += 8) {
        int eg = j + g;
        int se = esrc[eg < end ? eg : end - 1];
        const uint4* kh = (const uint4*)(K + (size_t)se * 128 + l * 16);
        uint4 k0 = kh[0], k1 = kh[1];
        unsigned vu[8];
        #pragma unroll
        for (int e = 0; e < 8; e++) {
            int sv = __shfl(se, e * 8);
            vu[e] = ((const unsigned*)(V + (size_t)sv * 128))[lane];
        }
        float p = (dot8f(q0, k0) + dot8f(q1, k1)) * SC;
        float mx = fmaxf(p, __shfl_xor(p, 1));
        mx = fmaxf(mx, __shfl_xor(mx, 2));
        mx = fmaxf(mx, __shfl_xor(mx, 4));
        float ex = exp2f(p - mx);
        float t = ex + __shfl_xor(ex, 1);
        t += __shfl_xor(t, 2);
        t += __shfl_xor(t, 4);
        float wgt = __fdividef(ex, t);
        #pragma unroll
        for (int e = 0; e < 8; e++) {
            float we = (j + e < end) ? __shfl(wgt, e * 8 + g) : 0.f;
            ax += we * blo(vu[e]);
            ay += we * bhi(vu[e]);
        }
    }
    __hip_bfloat162 o2;
    o2.x = __float2bfloat16(ax);
    o2.y = __float2bfloat16(ay);
    ((__hip_bfloat162*)(ag + (size_t)i * 128))[lane] = o2;
}

extern "C" void kernel_launch(void* const* d_in, const int* in_sizes, int n_in,
                              void* d_out, int out_size, void* d_ws, size_t ws_size,
                              hipStream_t stream) {
    const float* x   = (const float*)d_in[0];
    const int*  eidx = (const int*)d_in[1];
    const float* Wq = (const float*)d_in[2];  const float* bq = (const float*)d_in[3];
    const float* Wk = (const float*)d_in[4];  const float* bk = (const float*)d_in[5];
    const float* Wv = (const float*)d_in[6];  const float* bv = (const float*)d_in[7];
    const float* Wo = (const float*)d_in[8];  const float* bo = (const float*)d_in[9];
    const float* W1 = (const float*)d_in[10]; const float* b1 = (const float*)d_in[11];
    const float* W2 = (const float*)d_in[12]; const float* b2 = (const float*)d_in[13];
    const float* g1 = (const float*)d_in[14]; const float* be1 = (const float*)d_in[15];
    const float* g2 = (const float*)d_in[16]; const float* be2 = (const float*)d_in[17];
    float* out = (float*)d_out;

    int n  = in_sizes[0] / C_DIM;   // 100000
    int E_ = in_sizes[1] / 2;       // 600000
    size_t nf = (size_t)n * 128;

    // ---- workspace ----
    bf16* Wt    = (bf16*)d_ws;                // 196608 bf16 transposed weights
    float* bqkv = (float*)(Wt + 196608);      // packed [bq|bk|bv]
    bf16* reg0  = (bf16*)(bqkv + 384);        // 4*nf: h1|Q|K|V ; u overlays all
    bf16* h1 = reg0;
    bf16* Qb = reg0 + nf;
    bf16* Kb = reg0 + 2 * nf;
    bf16* Vb = reg0 + 3 * nf;
    bf16* uB = reg0;                          // [N,512] bf16 (FFN intermediate)
    bf16* ag = reg0 + 4 * nf;                 // [N,128]
    char* r2 = (char*)(ag + nf);              // union region
    int*  esrc   = (int*)r2;                  // [E] CSR-ordered source ids
    int*  ideg   = esrc + E_;
    int*  counter = ideg + n;
    int*  istart  = ideg + n + 1;
    int*  icursor = istart + n;
    bf16* h2 = (bf16*)r2;                     // overlays esrc/CSR after attn_aggr

    dim3 b256(256);
    dim3 lnGrid((n + 3) / 4);
    int rb = (n + 127) / 128;                 // 782
    dim3 eGrid((E_ + 255) / 256);
    dim3 nGrid((n + 255) / 256);
    dim3 n1Grid((n + 1 + 255) / 256);
    dim3 n4Grid((n + 3) / 4);

    // weights -> bf16 transposed + packed bqkv (one dispatch)
    wconv_all<<<dim3(770), b256, 0, stream>>>(Wq, Wk, Wv, Wo, W1, W2, bq, bk, bv, Wt);
    // zero deg+counter
    zeroi_kernel<<<n1Grid, b256, 0, stream>>>(ideg, n + 1);
    // LN1: x -> h1
    ln_kernel<<<lnGrid, b256, 0, stream>>>(x, g1, be1, h1, n);
    // QKV: one dispatch, col-blocks -> Q|K|V buffers (obStride = nf)
    gemm_lds<true, false, false, 1><<<dim3(rb, 3), b256, 0, stream>>>(
        h1, 128, Wt, 128, bqkv, Qb, 128, nf, nullptr, 0, n, nullptr, nullptr, nullptr);
    // CSR build
    hist_kernel<<<eGrid, b256, 0, stream>>>(eidx, ideg, E_);
    alloc_kernel<<<nGrid, b256, 0, stream>>>(ideg, istart, icursor, counter, n);
    scatter_kernel<<<eGrid, b256, 0, stream>>>(eidx, icursor, esrc, E_);
    // fused attention + aggregation into ag
    attn_aggr_kernel<<<n4Grid, b256, 0, stream>>>(Qb, Kb, Vb, istart, ideg, esrc, ag, n);
    // Wo + residual + fused LN2: x2 -> d_out (fp32), h2 (bf16, overlays r2)
    gemm_lds<false, false, true, 1><<<dim3(rb, 1), b256, 0, stream>>>(
        ag, 128, Wt + 49152, 128, bo, out, 128, 0, x, 128, n, g2, be2, h2);
    // FFN1: h2 @ W1 + b1, ReLU -> u [N,512] bf16 (overlays h1|Q|K|V, all dead)
    gemm_lds<true, true, false, 1><<<dim3(rb, 4), b256, 0, stream>>>(
        h2, 128, Wt + 65536, 128, b1, uB, 512, 128, nullptr, 0, n, nullptr, nullptr, nullptr);
    // FFN2: u @ W2 + b2 + x2 -> d_out (K=512 -> 4 k-tiles)
    gemm_lds<false, false, false, 4><<<dim3(rb, 1), b256, 0, stream>>>(
        uB, 512, Wt + 131072, 512, b2, out, 128, 0, out, 128, n, nullptr, nullptr, nullptr);
}

// Round 9
// 464.209 us; speedup vs baseline: 1.2727x; 1.2727x over previous
//
#include <hip/hip_runtime.h>
#include <hip/hip_bf16.h>

#define C_DIM 128
#define EPS_LN 1e-5f

typedef short bf16x8 __attribute__((ext_vector_type(8)));
typedef float f32x4  __attribute__((ext_vector_type(4)));
typedef __hip_bfloat16 bf16;

__device__ inline unsigned short f2bu(float f) {
    bf16 h = __float2bfloat16(f);
    return *reinterpret_cast<unsigned short*>(&h);
}
__device__ inline float blo(unsigned int u) { return __uint_as_float(u << 16); }
__device__ inline float bhi(unsigned int u) { return __uint_as_float(u & 0xffff0000u); }
__device__ inline ushort4 pack4(float a, float b, float c, float d) {
    ushort4 r; r.x = f2bu(a); r.y = f2bu(b); r.z = f2bu(c); r.w = f2bu(d); return r;
}

// async global->LDS DMA, 16B per lane. LDS dest is WAVE-UNIFORM base;
// HW writes lane l's 16B at base + l*16. Global src is per-lane.
__device__ inline void async_copy16(const bf16* g, bf16* s) {
    __builtin_amdgcn_global_load_lds(
        (const __attribute__((address_space(1))) unsigned int*)g,
        (__attribute__((address_space(3))) unsigned int*)s,
        16, 0, 0);
}

// ---------------- weights convert+transpose + bias pack, ONE dispatch ------
// dst (bf16): Wqt|Wkt|Wvt|Wot (4x 128*128) | Wt1[512][128] | Wt2[128][512]
// then packed fp32 bqkv[384] right after.
__global__ __launch_bounds__(256) void wconv_all(
    const float* __restrict__ Wq, const float* __restrict__ Wk,
    const float* __restrict__ Wv, const float* __restrict__ Wo,
    const float* __restrict__ W1, const float* __restrict__ W2,
    const float* __restrict__ bq, const float* __restrict__ bk,
    const float* __restrict__ bv, bf16* __restrict__ dst) {
    int idx = blockIdx.x * 256 + threadIdx.x;
    if (idx < 65536) {                       // four 128x128 weights
        int r = idx >> 14, o = idx & 16383;
        int k = o >> 7, nn = o & 127;
        const float* W = (r == 0) ? Wq : (r == 1) ? Wk : (r == 2) ? Wv : Wo;
        dst[(r << 14) + nn * 128 + k] = __float2bfloat16(W[o]);
    } else if (idx < 131072) {               // W1 [128,512] -> Wt1[n][k]
        int o = idx - 65536;
        int k = o >> 9, nn = o & 511;
        dst[65536 + nn * 128 + k] = __float2bfloat16(W1[o]);
    } else if (idx < 196608) {               // W2 [512,128] -> Wt2[n][k]
        int o = idx - 131072;
        int k = o >> 7, nn = o & 127;
        dst[131072 + nn * 512 + k] = __float2bfloat16(W2[o]);
    } else if (idx < 196992) {               // packed bqkv[384] fp32
        int j = idx - 196608;
        int grp = j >> 7, col = j & 127;
        const float* bp = (grp == 0) ? bq : (grp == 1) ? bk : bv;
        ((float*)(dst + 196608))[j] = bp[col];
    }
}

__global__ __launch_bounds__(256) void zeroi_kernel(int* __restrict__ p, int n) {
    int i = blockIdx.x * 256 + threadIdx.x;
    if (i < n) p[i] = 0;
}

// ---------------- LayerNorm fp32 -> bf16, one wave per row -----------------
__global__ __launch_bounds__(256) void ln_kernel(
    const float* __restrict__ x, const float* __restrict__ g,
    const float* __restrict__ b, bf16* __restrict__ out, int n) {
    int wave = threadIdx.x >> 6;
    int lane = threadIdx.x & 63;
    int row = blockIdx.x * 4 + wave;
    if (row >= n) return;
    float2 v = ((const float2*)(x + (size_t)row * C_DIM))[lane];
    float s  = v.x + v.y;
    float ss = v.x * v.x + v.y * v.y;
    #pragma unroll
    for (int o = 1; o < 64; o <<= 1) {
        s  += __shfl_xor(s, o);
        ss += __shfl_xor(ss, o);
    }
    float mu  = s * (1.0f / C_DIM);
    float var = ss * (1.0f / C_DIM) - mu * mu;
    float rs  = rsqrtf(var + EPS_LN);
    float2 gg = ((const float2*)g)[lane];
    float2 bb = ((const float2*)b)[lane];
    __hip_bfloat162 o2;
    o2.x = __float2bfloat16((v.x - mu) * rs * gg.x + bb.x);
    o2.y = __float2bfloat16((v.y - mu) * rs * gg.y + bb.y);
    ((__hip_bfloat162*)(out + (size_t)row * C_DIM))[lane] = o2;
}

// ---------------- LDS-staged MFMA GEMM, BK=64 (global_load_lds + swizzle) --
// Block: 128 rows x 128 cols of C; 4 waves, each 32 rows x 128 cols.
// A [M,lda] bf16 row-major; Bt [Ncols][Kfull] bf16 (row = output col).
// Round-9: BK 128->64. LDS 64->32KB -> 4-5 blocks/CU (was 2). Same staged
// bytes, same grid, but more resident blocks stagger the per-block
// stage/drain/compute/write phases -> higher effective staging rate.
// (r3: A must stay on DMA path; r8: B must stay on DMA path; r7: grid must
// stay fine-grained. BK is the only free structural parameter.)
// Staging: async_copy16; per call lane l covers row (l>>3), 16B-slot (l&7);
// LDS slot s of row r holds global slot s^(r&7). Reads use
// ((ks*4+q)^(m&7))<<3 with ks in {0,1} -> same bank-uniform pattern.
// Tail: clamp A source row to M-1 (garbage masked in epilogue).
// KSTEPS counts 64-wide k-tiles (K=128 -> 2, K=512 -> 8).
// Operand-swapped mfma(bf, af, acc): lane(m,q) reg r = C[row0+..+m][ct*16+q*4+r].
template<bool OUTBF16, bool RELU, bool FUSE_LN, int KSTEPS>
__global__ __launch_bounds__(256) void gemm_lds(
    const bf16* __restrict__ A, int lda,
    const bf16* __restrict__ Bt, int Kfull,
    const float* __restrict__ biasBase,
    void* __restrict__ Cd, int ldc, size_t obStride,
    const float* __restrict__ resid, int ldres,
    int M,
    const float* __restrict__ g, const float* __restrict__ be,
    bf16* __restrict__ h2) {
    __shared__ bf16 As[128][64];
    __shared__ bf16 Bs[128][64];
    int tid  = threadIdx.x;
    int lane = tid & 63;
    int w    = tid >> 6;
    int m = lane & 15, q = lane >> 4;
    int row0 = blockIdx.x * 128;
    const bf16* Bbase = Bt + (size_t)blockIdx.y * 128 * Kfull;

    f32x4 acc[2][8];
    #pragma unroll
    for (int rt = 0; rt < 2; rt++)
        #pragma unroll
        for (int ct = 0; ct < 8; ct++) acc[rt][ct] = (f32x4){0.f, 0.f, 0.f, 0.f};

    int rsub  = lane >> 3;      // 0..7: this lane's dest row within an 8-row DMA call
    int cslot = lane & 7;       // this lane's 16B slot within the 64-col row

    for (int kt = 0; kt < KSTEPS; kt++) {
        // stage A+B tiles [128][64] via 4+4 async DMA calls per wave
        #pragma unroll
        for (int i = 0; i < 4; i++) {
            int arow = w * 32 + i * 8 + rsub;                 // dest row 0..127
            int scol = (cslot ^ (arow & 7)) << 3;             // swizzled src slot (elems)
            int garow = row0 + arow;
            if (garow > M - 1) garow = M - 1;                 // tail clamp
            async_copy16(A + (size_t)garow * lda + kt * 64 + scol, &As[w * 32 + i * 8][0]);
            async_copy16(Bbase + (size_t)arow * Kfull + kt * 64 + scol, &Bs[w * 32 + i * 8][0]);
        }
        __syncthreads();
        #pragma unroll
        for (int ks = 0; ks < 2; ks++) {
            int sofs = ((ks * 4 + q) ^ (m & 7)) << 3;         // swizzled read offset
            bf16x8 af0 = *(const bf16x8*)&As[w * 32 + m][sofs];
            bf16x8 af1 = *(const bf16x8*)&As[w * 32 + 16 + m][sofs];
            #pragma unroll
            for (int ct = 0; ct < 8; ct++) {
                bf16x8 bf = *(const bf16x8*)&Bs[ct * 16 + m][sofs];
                acc[0][ct] = __builtin_amdgcn_mfma_f32_16x16x32_bf16(bf, af0, acc[0][ct], 0, 0, 0);
                acc[1][ct] = __builtin_amdgcn_mfma_f32_16x16x32_bf16(bf, af1, acc[1][ct], 0, 0, 0);
            }
        }
        if (kt + 1 < KSTEPS) __syncthreads();
    }

    // ---- epilogue ----
    #pragma unroll
    for (int rt = 0; rt < 2; rt++) {
        int row = row0 + w * 32 + rt * 16 + m;
        bool valid = row < M;
        float vals[8][4];
        #pragma unroll
        for (int ct = 0; ct < 8; ct++) {
            int col = ct * 16 + q * 4;
            float4 bv = make_float4(0.f, 0.f, 0.f, 0.f);
            if (biasBase) bv = *(const float4*)(biasBase + blockIdx.y * 128 + col);
            float4 rv = make_float4(0.f, 0.f, 0.f, 0.f);
            if (resid && valid) rv = *(const float4*)(resid + (size_t)row * ldres + col);
            vals[ct][0] = acc[rt][ct][0] + bv.x + rv.x;
            vals[ct][1] = acc[rt][ct][1] + bv.y + rv.y;
            vals[ct][2] = acc[rt][ct][2] + bv.z + rv.z;
            vals[ct][3] = acc[rt][ct][3] + bv.w + rv.w;
        }
        if (FUSE_LN) {
            // row spans lanes {m, m+16, m+32, m+48}: reduce over q via xor 16,32
            float s1 = 0.f, s2 = 0.f;
            #pragma unroll
            for (int ct = 0; ct < 8; ct++)
                #pragma unroll
                for (int r = 0; r < 4; r++) { s1 += vals[ct][r]; s2 += vals[ct][r] * vals[ct][r]; }
            s1 += __shfl_xor(s1, 16); s1 += __shfl_xor(s1, 32);
            s2 += __shfl_xor(s2, 16); s2 += __shfl_xor(s2, 32);
            float mu  = s1 * (1.0f / 128.f);
            float var = s2 * (1.0f / 128.f) - mu * mu;
            float rs  = rsqrtf(var + EPS_LN);
            if (valid) {
                #pragma unroll
                for (int ct = 0; ct < 8; ct++) {
                    int col = ct * 16 + q * 4;
                    *(float4*)((float*)Cd + (size_t)row * ldc + col) =
                        make_float4(vals[ct][0], vals[ct][1], vals[ct][2], vals[ct][3]);
                    float4 gg = *(const float4*)(g + col);
                    float4 bb = *(const float4*)(be + col);
                    *(ushort4*)(h2 + (size_t)row * 128 + col) =
                        pack4((vals[ct][0] - mu) * rs * gg.x + bb.x,
                              (vals[ct][1] - mu) * rs * gg.y + bb.y,
                              (vals[ct][2] - mu) * rs * gg.z + bb.z,
                              (vals[ct][3] - mu) * rs * gg.w + bb.w);
                }
            }
        } else if (valid) {
            #pragma unroll
            for (int ct = 0; ct < 8; ct++) {
                int col = ct * 16 + q * 4;
                float v0 = vals[ct][0], v1 = vals[ct][1];
                float v2 = vals[ct][2], v3 = vals[ct][3];
                if (RELU) {
                    v0 = fmaxf(v0, 0.f); v1 = fmaxf(v1, 0.f);
                    v2 = fmaxf(v2, 0.f); v3 = fmaxf(v3, 0.f);
                }
                if (OUTBF16) {
                    *(ushort4*)((bf16*)Cd + blockIdx.y * obStride + (size_t)row * ldc + col) =
                        pack4(v0, v1, v2, v3);
                } else {
                    *(float4*)((float*)Cd + blockIdx.y * obStride + (size_t)row * ldc + col) =
                        make_float4(v0, v1, v2, v3);
                }
            }
        }
    }
}

// ---------------- CSR build ------------------------------------------------
__global__ __launch_bounds__(256) void hist_kernel(
    const int* __restrict__ eidx, int* __restrict__ deg, int E_) {
    int e = blockIdx.x * 256 + threadIdx.x;
    if (e >= E_) return;
    atomicAdd(&deg[eidx[E_ + e]], 1);
}

__global__ __launch_bounds__(256) void alloc_kernel(
    const int* __restrict__ deg, int* __restrict__ start,
    int* __restrict__ cursor, int* __restrict__ counter, int n) {
    int i = blockIdx.x * 256 + threadIdx.x;
    if (i >= n) return;
    int d = deg[i];
    int s = atomicAdd(counter, d);
    start[i] = s;
    cursor[i] = s;
}

__global__ __launch_bounds__(256) void scatter_kernel(
    const int* __restrict__ eidx, int* __restrict__ cursor,
    int* __restrict__ esrc, int E_) {
    int e = blockIdx.x * 256 + threadIdx.x;
    if (e >= E_) return;
    int src = eidx[e];
    int dst = eidx[E_ + e];
    int pos = atomicAdd(&cursor[dst], 1);
    esrc[pos] = src;
}

// ---------- fused attention + aggregation: one wave per node ---------------
// (round-6 state: K + all-8-V loads issued together -> one exposed gather
// round; predicated phase 2, no branches; exp2f folded scale; fast div.)
__device__ inline float dot8f(uint4 a, uint4 b) {
    return blo(a.x) * blo(b.x) + bhi(a.x) * bhi(b.x)
         + blo(a.y) * blo(b.y) + bhi(a.y) * bhi(b.y)
         + blo(a.z) * blo(b.z) + bhi(a.z) * bhi(b.z)
         + blo(a.w) * blo(b.w) + bhi(a.w) * bhi(b.w);
}

__global__ __launch_bounds__(256) void attn_aggr_kernel(
    const bf16* __restrict__ Q, const bf16* __restrict__ K,
    const bf16* __restrict__ V,
    const int* __restrict__ start, const int* __restrict__ deg,
    const int* __restrict__ esrc, bf16* __restrict__ ag, int n) {
    int wave = threadIdx.x >> 6;
    int lane = threadIdx.x & 63;
    int i = blockIdx.x * 4 + wave;
    if (i >= n) return;
    int s = start[i], d = deg[i];
    int end = s + d;
    int g = lane >> 3;          // edge slot within 8-batch (== head in phase 2)
    int l = lane & 7;           // head owned in phase 1
    const uint4* qh = (const uint4*)(Q + (size_t)i * 128 + l * 16);
    uint4 q0 = qh[0], q1 = qh[1];
    const float SC = 0.25f * 1.44269504089f;   // /sqrt(16) * log2(e)
    float ax = 0.f, ay = 0.f;
    for (int j = s; j < end; j += 8) {
        int eg = j + g;
        int se = esrc[eg < end ? eg : end - 1];
        const uint4* kh = (const uint4*)(K + (size_t)se * 128 + l * 16);
        uint4 k0 = kh[0], k1 = kh[1];
        unsigned vu[8];
        #pragma unroll
        for (int e = 0; e < 8; e++) {
            int sv = __shfl(se, e * 8);
            vu[e] = ((const unsigned*)(V + (size_t)sv * 128))[lane];
        }
        float p = (dot8f(q0, k0) + dot8f(q1, k1)) * SC;
        float mx = fmaxf(p, __shfl_xor(p, 1));
        mx = fmaxf(mx, __shfl_xor(mx, 2));
        mx = fmaxf(mx, __shfl_xor(mx, 4));
        float ex = exp2f(p - mx);
        float t = ex + __shfl_xor(ex, 1);
        t += __shfl_xor(t, 2);
        t += __shfl_xor(t, 4);
        float wgt = __fdividef(ex, t);
        #pragma unroll
        for (int e = 0; e < 8; e++) {
            float we = (j + e < end) ? __shfl(wgt, e * 8 + g) : 0.f;
            ax += we * blo(vu[e]);
            ay += we * bhi(vu[e]);
        }
    }
    __hip_bfloat162 o2;
    o2.x = __float2bfloat16(ax);
    o2.y = __float2bfloat16(ay);
    ((__hip_bfloat162*)(ag + (size_t)i * 128))[lane] = o2;
}

extern "C" void kernel_launch(void* const* d_in, const int* in_sizes, int n_in,
                              void* d_out, int out_size, void* d_ws, size_t ws_size,
                              hipStream_t stream) {
    const float* x   = (const float*)d_in[0];
    const int*  eidx = (const int*)d_in[1];
    const float* Wq = (const float*)d_in[2];  const float* bq = (const float*)d_in[3];
    const float* Wk = (const float*)d_in[4];  const float* bk = (const float*)d_in[5];
    const float* Wv = (const float*)d_in[6];  const float* bv = (const float*)d_in[7];
    const float* Wo = (const float*)d_in[8];  const float* bo = (const float*)d_in[9];
    const float* W1 = (const float*)d_in[10]; const float* b1 = (const float*)d_in[11];
    const float* W2 = (const float*)d_in[12]; const float* b2 = (const float*)d_in[13];
    const float* g1 = (const float*)d_in[14]; const float* be1 = (const float*)d_in[15];
    const float* g2 = (const float*)d_in[16]; const float* be2 = (const float*)d_in[17];
    float* out = (float*)d_out;

    int n  = in_sizes[0] / C_DIM;   // 100000
    int E_ = in_sizes[1] / 2;       // 600000
    size_t nf = (size_t)n * 128;

    // ---- workspace ----
    bf16* Wt    = (bf16*)d_ws;                // 196608 bf16 transposed weights
    float* bqkv = (float*)(Wt + 196608);      // packed [bq|bk|bv]
    bf16* reg0  = (bf16*)(bqkv + 384);        // 4*nf: h1|Q|K|V ; u overlays all
    bf16* h1 = reg0;
    bf16* Qb = reg0 + nf;
    bf16* Kb = reg0 + 2 * nf;
    bf16* Vb = reg0 + 3 * nf;
    bf16* uB = reg0;                          // [N,512] bf16 (FFN intermediate)
    bf16* ag = reg0 + 4 * nf;                 // [N,128]
    char* r2 = (char*)(ag + nf);              // union region
    int*  esrc   = (int*)r2;                  // [E] CSR-ordered source ids
    int*  ideg   = esrc + E_;
    int*  counter = ideg + n;
    int*  istart  = ideg + n + 1;
    int*  icursor = istart + n;
    bf16* h2 = (bf16*)r2;                     // overlays esrc/CSR after attn_aggr

    dim3 b256(256);
    dim3 lnGrid((n + 3) / 4);
    int rb = (n + 127) / 128;                 // 782
    dim3 eGrid((E_ + 255) / 256);
    dim3 nGrid((n + 255) / 256);
    dim3 n1Grid((n + 1 + 255) / 256);
    dim3 n4Grid((n + 3) / 4);

    // weights -> bf16 transposed + packed bqkv (one dispatch)
    wconv_all<<<dim3(770), b256, 0, stream>>>(Wq, Wk, Wv, Wo, W1, W2, bq, bk, bv, Wt);
    // zero deg+counter
    zeroi_kernel<<<n1Grid, b256, 0, stream>>>(ideg, n + 1);
    // LN1: x -> h1
    ln_kernel<<<lnGrid, b256, 0, stream>>>(x, g1, be1, h1, n);
    // QKV: one dispatch, col-blocks -> Q|K|V buffers (obStride = nf); K=128 -> 2 k-tiles
    gemm_lds<true, false, false, 2><<<dim3(rb, 3), b256, 0, stream>>>(
        h1, 128, Wt, 128, bqkv, Qb, 128, nf, nullptr, 0, n, nullptr, nullptr, nullptr);
    // CSR build
    hist_kernel<<<eGrid, b256, 0, stream>>>(eidx, ideg, E_);
    alloc_kernel<<<nGrid, b256, 0, stream>>>(ideg, istart, icursor, counter, n);
    scatter_kernel<<<eGrid, b256, 0, stream>>>(eidx, icursor, esrc, E_);
    // fused attention + aggregation into ag
    attn_aggr_kernel<<<n4Grid, b256, 0, stream>>>(Qb, Kb, Vb, istart, ideg, esrc, ag, n);
    // Wo + residual + fused LN2: x2 -> d_out (fp32), h2 (bf16, overlays r2)
    gemm_lds<false, false, true, 2><<<dim3(rb, 1), b256, 0, stream>>>(
        ag, 128, Wt + 49152, 128, bo, out, 128, 0, x, 128, n, g2, be2, h2);
    // FFN1: h2 @ W1 + b1, ReLU -> u [N,512] bf16 (overlays h1|Q|K|V, all dead)
    gemm_lds<true, true, false, 2><<<dim3(rb, 4), b256, 0, stream>>>(
        h2, 128, Wt + 65536, 128, b1, uB, 512, 128, nullptr, 0, n, nullptr, nullptr, nullptr);
    // FFN2: u @ W2 + b2 + x2 -> d_out (K=512 -> 8 k-tiles)
    gemm_lds<false, false, false, 8><<<dim3(rb, 1), b256, 0, stream>>>(
        uB, 512, Wt + 131072, 512, b2, out, 128, 0, out, 128, n, nullptr, nullptr, nullptr);
}

// Round 10
// 457.516 us; speedup vs baseline: 1.2913x; 1.0146x over previous
//
#include <hip/hip_runtime.h>
#include <hip/hip_bf16.h>

#define C_DIM 128
#define EPS_LN 1e-5f

typedef short bf16x8 __attribute__((ext_vector_type(8)));
typedef float f32x4  __attribute__((ext_vector_type(4)));
typedef __hip_bfloat16 bf16;

__device__ inline unsigned short f2bu(float f) {
    bf16 h = __float2bfloat16(f);
    return *reinterpret_cast<unsigned short*>(&h);
}
__device__ inline float blo(unsigned int u) { return __uint_as_float(u << 16); }
__device__ inline float bhi(unsigned int u) { return __uint_as_float(u & 0xffff0000u); }
__device__ inline ushort4 pack4(float a, float b, float c, float d) {
    ushort4 r; r.x = f2bu(a); r.y = f2bu(b); r.z = f2bu(c); r.w = f2bu(d); return r;
}

// async global->LDS DMA, 16B per lane. LDS dest is WAVE-UNIFORM base;
// HW writes lane l's 16B at base + l*16. Global src is per-lane.
__device__ inline void async_copy16(const bf16* g, bf16* s) {
    __builtin_amdgcn_global_load_lds(
        (const __attribute__((address_space(1))) unsigned int*)g,
        (__attribute__((address_space(3))) unsigned int*)s,
        16, 0, 0);
}

// -------- weights convert+transpose + bias pack + deg zero, ONE dispatch ---
// Blocks [0,770): dst (bf16): Wqt|Wkt|Wvt|Wot (4x 128*128) | Wt1[512][128] |
// Wt2[128][512], then packed fp32 bqkv[384]. Blocks [770,...): zero deg[n+1].
__global__ __launch_bounds__(256) void wconv_zero(
    const float* __restrict__ Wq, const float* __restrict__ Wk,
    const float* __restrict__ Wv, const float* __restrict__ Wo,
    const float* __restrict__ W1, const float* __restrict__ W2,
    const float* __restrict__ bq, const float* __restrict__ bk,
    const float* __restrict__ bv, bf16* __restrict__ dst,
    int* __restrict__ deg, int nn1) {
    if (blockIdx.x >= 770) {
        int i = (blockIdx.x - 770) * 256 + threadIdx.x;
        if (i < nn1) deg[i] = 0;
        return;
    }
    int idx = blockIdx.x * 256 + threadIdx.x;
    if (idx < 65536) {                       // four 128x128 weights
        int r = idx >> 14, o = idx & 16383;
        int k = o >> 7, nn = o & 127;
        const float* W = (r == 0) ? Wq : (r == 1) ? Wk : (r == 2) ? Wv : Wo;
        dst[(r << 14) + nn * 128 + k] = __float2bfloat16(W[o]);
    } else if (idx < 131072) {               // W1 [128,512] -> Wt1[n][k]
        int o = idx - 65536;
        int k = o >> 9, nn = o & 511;
        dst[65536 + nn * 128 + k] = __float2bfloat16(W1[o]);
    } else if (idx < 196608) {               // W2 [512,128] -> Wt2[n][k]
        int o = idx - 131072;
        int k = o >> 7, nn = o & 127;
        dst[131072 + nn * 512 + k] = __float2bfloat16(W2[o]);
    } else if (idx < 196992) {               // packed bqkv[384] fp32
        int j = idx - 196608;
        int grp = j >> 7, col = j & 127;
        const float* bp = (grp == 0) ? bq : (grp == 1) ? bk : bv;
        ((float*)(dst + 196608))[j] = bp[col];
    }
}

// -------- LayerNorm fp32 -> bf16 (blocks < lnBlocks) + degree histogram ----
// hist part requires deg zeroed: guaranteed by preceding wconv_zero dispatch.
__global__ __launch_bounds__(256) void ln_hist(
    const float* __restrict__ x, const float* __restrict__ g,
    const float* __restrict__ b, bf16* __restrict__ out, int n,
    const int* __restrict__ eidx, int* __restrict__ deg, int E_, int lnBlocks) {
    if (blockIdx.x >= lnBlocks) {
        int e = (blockIdx.x - lnBlocks) * 256 + threadIdx.x;
        if (e < E_) atomicAdd(&deg[eidx[E_ + e]], 1);
        return;
    }
    int wave = threadIdx.x >> 6;
    int lane = threadIdx.x & 63;
    int row = blockIdx.x * 4 + wave;
    if (row >= n) return;
    float2 v = ((const float2*)(x + (size_t)row * C_DIM))[lane];
    float s  = v.x + v.y;
    float ss = v.x * v.x + v.y * v.y;
    #pragma unroll
    for (int o = 1; o < 64; o <<= 1) {
        s  += __shfl_xor(s, o);
        ss += __shfl_xor(ss, o);
    }
    float mu  = s * (1.0f / C_DIM);
    float var = ss * (1.0f / C_DIM) - mu * mu;
    float rs  = rsqrtf(var + EPS_LN);
    float2 gg = ((const float2*)g)[lane];
    float2 bb = ((const float2*)b)[lane];
    __hip_bfloat162 o2;
    o2.x = __float2bfloat16((v.x - mu) * rs * gg.x + bb.x);
    o2.y = __float2bfloat16((v.y - mu) * rs * gg.y + bb.y);
    ((__hip_bfloat162*)(out + (size_t)row * C_DIM))[lane] = o2;
}

// ---------------- LDS-staged MFMA GEMM (global_load_lds + XOR swizzle) -----
// ROUND-6 KNOWN-GOOD STATE. Block: 128 rows x 128 cols of C; 4 waves.
// A [M,lda] bf16 row-major; Bt [Ncols][Kfull] bf16 (row = output col).
// Staging: async_copy16, wave-uniform LDS base (linear [128][128]), per-lane
// global src pre-swizzled: LDS slot s of row r holds global slot s^(r&7).
// Reads use ((ks*4+q)^(m&7))<<3 -> bank-uniform (2 lanes/bank, free).
// Tail: clamp source row to M-1 (garbage lands only in C rows >= M, masked).
// Parameter space exhausted (measured): A-direct-to-reg (r3: HBM overfetch),
// in-block col loop NCB (r7: parallelism collapse), B-direct-L2 (r8: latency
// not hidden), BK=64 (r9: drain not occupancy-maskable). Keep BK=128/2-block.
// Operand-swapped mfma(bf, af, acc): lane(m,q) reg r = C[row0+..+m][ct*16+q*4+r].
template<bool OUTBF16, bool RELU, bool FUSE_LN, int KSTEPS>
__global__ __launch_bounds__(256) void gemm_lds(
    const bf16* __restrict__ A, int lda,
    const bf16* __restrict__ Bt, int Kfull,
    const float* __restrict__ biasBase,
    void* __restrict__ Cd, int ldc, size_t obStride,
    const float* __restrict__ resid, int ldres,
    int M,
    const float* __restrict__ g, const float* __restrict__ be,
    bf16* __restrict__ h2) {
    __shared__ bf16 As[128][128];
    __shared__ bf16 Bs[128][128];
    int tid  = threadIdx.x;
    int lane = tid & 63;
    int w    = tid >> 6;
    int m = lane & 15, q = lane >> 4;
    int row0 = blockIdx.x * 128;
    const bf16* Bbase = Bt + (size_t)blockIdx.y * 128 * Kfull;

    f32x4 acc[2][8];
    #pragma unroll
    for (int rt = 0; rt < 2; rt++)
        #pragma unroll
        for (int ct = 0; ct < 8; ct++) acc[rt][ct] = (f32x4){0.f, 0.f, 0.f, 0.f};

    int rsub  = lane >> 4;      // 0..3: this lane's dest row within a 4-row DMA call
    int cslot = lane & 15;      // this lane's 16B slot within the row

    for (int kt = 0; kt < KSTEPS; kt++) {
        // stage A+B tiles [128][128] via 8+8 async DMA calls per wave
        #pragma unroll
        for (int i = 0; i < 8; i++) {
            int arow = w * 32 + i * 4 + rsub;                 // dest row 0..127
            int scol = (cslot ^ (arow & 7)) << 3;             // swizzled src slot (elems)
            int garow = row0 + arow;
            if (garow > M - 1) garow = M - 1;                 // tail clamp
            async_copy16(A + (size_t)garow * lda + kt * 128 + scol, &As[w * 32 + i * 4][0]);
            async_copy16(Bbase + (size_t)arow * Kfull + kt * 128 + scol, &Bs[w * 32 + i * 4][0]);
        }
        __syncthreads();
        #pragma unroll
        for (int ks = 0; ks < 4; ks++) {
            int sofs = ((ks * 4 + q) ^ (m & 7)) << 3;         // swizzled read offset
            bf16x8 af0 = *(const bf16x8*)&As[w * 32 + m][sofs];
            bf16x8 af1 = *(const bf16x8*)&As[w * 32 + 16 + m][sofs];
            #pragma unroll
            for (int ct = 0; ct < 8; ct++) {
                bf16x8 bf = *(const bf16x8*)&Bs[ct * 16 + m][sofs];
                acc[0][ct] = __builtin_amdgcn_mfma_f32_16x16x32_bf16(bf, af0, acc[0][ct], 0, 0, 0);
                acc[1][ct] = __builtin_amdgcn_mfma_f32_16x16x32_bf16(bf, af1, acc[1][ct], 0, 0, 0);
            }
        }
        if (kt + 1 < KSTEPS) __syncthreads();
    }

    // ---- epilogue ----
    #pragma unroll
    for (int rt = 0; rt < 2; rt++) {
        int row = row0 + w * 32 + rt * 16 + m;
        bool valid = row < M;
        float vals[8][4];
        #pragma unroll
        for (int ct = 0; ct < 8; ct++) {
            int col = ct * 16 + q * 4;
            float4 bv = make_float4(0.f, 0.f, 0.f, 0.f);
            if (biasBase) bv = *(const float4*)(biasBase + blockIdx.y * 128 + col);
            float4 rv = make_float4(0.f, 0.f, 0.f, 0.f);
            if (resid && valid) rv = *(const float4*)(resid + (size_t)row * ldres + col);
            vals[ct][0] = acc[rt][ct][0] + bv.x + rv.x;
            vals[ct][1] = acc[rt][ct][1] + bv.y + rv.y;
            vals[ct][2] = acc[rt][ct][2] + bv.z + rv.z;
            vals[ct][3] = acc[rt][ct][3] + bv.w + rv.w;
        }
        if (FUSE_LN) {
            // row spans lanes {m, m+16, m+32, m+48}: reduce over q via xor 16,32
            float s1 = 0.f, s2 = 0.f;
            #pragma unroll
            for (int ct = 0; ct < 8; ct++)
                #pragma unroll
                for (int r = 0; r < 4; r++) { s1 += vals[ct][r]; s2 += vals[ct][r] * vals[ct][r]; }
            s1 += __shfl_xor(s1, 16); s1 += __shfl_xor(s1, 32);
            s2 += __shfl_xor(s2, 16); s2 += __shfl_xor(s2, 32);
            float mu  = s1 * (1.0f / 128.f);
            float var = s2 * (1.0f / 128.f) - mu * mu;
            float rs  = rsqrtf(var + EPS_LN);
            if (valid) {
                #pragma unroll
                for (int ct = 0; ct < 8; ct++) {
                    int col = ct * 16 + q * 4;
                    *(float4*)((float*)Cd + (size_t)row * ldc + col) =
                        make_float4(vals[ct][0], vals[ct][1], vals[ct][2], vals[ct][3]);
                    float4 gg = *(const float4*)(g + col);
                    float4 bb = *(const float4*)(be + col);
                    *(ushort4*)(h2 + (size_t)row * 128 + col) =
                        pack4((vals[ct][0] - mu) * rs * gg.x + bb.x,
                              (vals[ct][1] - mu) * rs * gg.y + bb.y,
                              (vals[ct][2] - mu) * rs * gg.z + bb.z,
                              (vals[ct][3] - mu) * rs * gg.w + bb.w);
                }
            }
        } else if (valid) {
            #pragma unroll
            for (int ct = 0; ct < 8; ct++) {
                int col = ct * 16 + q * 4;
                float v0 = vals[ct][0], v1 = vals[ct][1];
                float v2 = vals[ct][2], v3 = vals[ct][3];
                if (RELU) {
                    v0 = fmaxf(v0, 0.f); v1 = fmaxf(v1, 0.f);
                    v2 = fmaxf(v2, 0.f); v3 = fmaxf(v3, 0.f);
                }
                if (OUTBF16) {
                    *(ushort4*)((bf16*)Cd + blockIdx.y * obStride + (size_t)row * ldc + col) =
                        pack4(v0, v1, v2, v3);
                } else {
                    *(float4*)((float*)Cd + blockIdx.y * obStride + (size_t)row * ldc + col) =
                        make_float4(v0, v1, v2, v3);
                }
            }
        }
    }
}

// ---------------- CSR build (alloc + scatter; hist merged into ln_hist) ----
__global__ __launch_bounds__(256) void alloc_kernel(
    const int* __restrict__ deg, int* __restrict__ start,
    int* __restrict__ cursor, int* __restrict__ counter, int n) {
    int i = blockIdx.x * 256 + threadIdx.x;
    if (i >= n) return;
    int d = deg[i];
    int s = atomicAdd(counter, d);
    start[i] = s;
    cursor[i] = s;
}

__global__ __launch_bounds__(256) void scatter_kernel(
    const int* __restrict__ eidx, int* __restrict__ cursor,
    int* __restrict__ esrc, int E_) {
    int e = blockIdx.x * 256 + threadIdx.x;
    if (e >= E_) return;
    int src = eidx[e];
    int dst = eidx[E_ + e];
    int pos = atomicAdd(&cursor[dst], 1);
    esrc[pos] = src;
}

// ---------- fused attention + aggregation: one wave per node ---------------
// (round-6 state: K + all-8-V loads issued together -> one exposed gather
// round; predicated phase 2, no branches; exp2f folded scale; fast div.)
__device__ inline float dot8f(uint4 a, uint4 b) {
    return blo(a.x) * blo(b.x) + bhi(a.x) * bhi(b.x)
         + blo(a.y) * blo(b.y) + bhi(a.y) * bhi(b.y)
         + blo(a.z) * blo(b.z) + bhi(a.z) * bhi(b.z)
         + blo(a.w) * blo(b.w) + bhi(a.w) * bhi(b.w);
}

__global__ __launch_bounds__(256) void attn_aggr_kernel(
    const bf16* __restrict__ Q, const bf16* __restrict__ K,
    const bf16* __restrict__ V,
    const int* __restrict__ start, const int* __restrict__ deg,
    const int* __restrict__ esrc, bf16* __restrict__ ag, int n) {
    int wave = threadIdx.x >> 6;
    int lane = threadIdx.x & 63;
    int i = blockIdx.x * 4 + wave;
    if (i >= n) return;
    int s = start[i], d = deg[i];
    int end = s + d;
    int g = lane >> 3;          // edge slot within 8-batch (== head in phase 2)
    int l = lane & 7;           // head owned in phase 1
    const uint4* qh = (const uint4*)(Q + (size_t)i * 128 + l * 16);
    uint4 q0 = qh[0], q1 = qh[1];
    const float SC = 0.25f * 1.44269504089f;   // /sqrt(16) * log2(e)
    float ax = 0.f, ay = 0.f;
    for (int j = s; j < end; j += 8) {
        int eg = j + g;
        int se = esrc[eg < end ? eg : end - 1];
        const uint4* kh = (const uint4*)(K + (size_t)se * 128 + l * 16);
        uint4 k0 = kh[0], k1 = kh[1];
        unsigned vu[8];
        #pragma unroll
        for (int e = 0; e < 8; e++) {
            int sv = __shfl(se, e * 8);
            vu[e] = ((const unsigned*)(V + (size_t)sv * 128))[lane];
        }
        float p = (dot8f(q0, k0) + dot8f(q1, k1)) * SC;
        float mx = fmaxf(p, __shfl_xor(p, 1));
        mx = fmaxf(mx, __shfl_xor(mx, 2));
        mx = fmaxf(mx, __shfl_xor(mx, 4));
        float ex = exp2f(p - mx);
        float t = ex + __shfl_xor(ex, 1);
        t += __shfl_xor(t, 2);
        t += __shfl_xor(t, 4);
        float wgt = __fdividef(ex, t);
        #pragma unroll
        for (int e = 0; e < 8; e++) {
            float we = (j + e < end) ? __shfl(wgt, e * 8 + g) : 0.f;
            ax += we * blo(vu[e]);
            ay += we * bhi(vu[e]);
        }
    }
    __hip_bfloat162 o2;
    o2.x = __float2bfloat16(ax);
    o2.y = __float2bfloat16(ay);
    ((__hip_bfloat162*)(ag + (size_t)i * 128))[lane] = o2;
}

extern "C" void kernel_launch(void* const* d_in, const int* in_sizes, int n_in,
                              void* d_out, int out_size, void* d_ws, size_t ws_size,
                              hipStream_t stream) {
    const float* x   = (const float*)d_in[0];
    const int*  eidx = (const int*)d_in[1];
    const float* Wq = (const float*)d_in[2];  const float* bq = (const float*)d_in[3];
    const float* Wk = (const float*)d_in[4];  const float* bk = (const float*)d_in[5];
    const float* Wv = (const float*)d_in[6];  const float* bv = (const float*)d_in[7];
    const float* Wo = (const float*)d_in[8];  const float* bo = (const float*)d_in[9];
    const float* W1 = (const float*)d_in[10]; const float* b1 = (const float*)d_in[11];
    const float* W2 = (const float*)d_in[12]; const float* b2 = (const float*)d_in[13];
    const float* g1 = (const float*)d_in[14]; const float* be1 = (const float*)d_in[15];
    const float* g2 = (const float*)d_in[16]; const float* be2 = (const float*)d_in[17];
    float* out = (float*)d_out;

    int n  = in_sizes[0] / C_DIM;   // 100000
    int E_ = in_sizes[1] / 2;       // 600000
    size_t nf = (size_t)n * 128;

    // ---- workspace ----
    bf16* Wt    = (bf16*)d_ws;                // 196608 bf16 transposed weights
    float* bqkv = (float*)(Wt + 196608);      // packed [bq|bk|bv]
    bf16* reg0  = (bf16*)(bqkv + 384);        // 4*nf: h1|Q|K|V ; u overlays all
    bf16* h1 = reg0;
    bf16* Qb = reg0 + nf;
    bf16* Kb = reg0 + 2 * nf;
    bf16* Vb = reg0 + 3 * nf;
    bf16* uB = reg0;                          // [N,512] bf16 (FFN intermediate)
    bf16* ag = reg0 + 4 * nf;                 // [N,128]
    char* r2 = (char*)(ag + nf);              // union region
    int*  esrc   = (int*)r2;                  // [E] CSR-ordered source ids
    int*  ideg   = esrc + E_;
    int*  counter = ideg + n;
    int*  istart  = ideg + n + 1;
    int*  icursor = istart + n;
    bf16* h2 = (bf16*)r2;                     // overlays esrc/CSR after attn_aggr

    dim3 b256(256);
    int lnBlocks = (n + 3) / 4;               // 25000
    int histBlocks = (E_ + 255) / 256;        // 2344
    int zeroBlocks = (n + 1 + 255) / 256;     // 391
    int rb = (n + 127) / 128;                 // 782
    dim3 eGrid((E_ + 255) / 256);
    dim3 nGrid((n + 255) / 256);
    dim3 n4Grid((n + 3) / 4);

    // weights -> bf16 transposed + packed bqkv + zero deg (one dispatch)
    wconv_zero<<<dim3(770 + zeroBlocks), b256, 0, stream>>>(
        Wq, Wk, Wv, Wo, W1, W2, bq, bk, bv, Wt, ideg, n + 1);
    // LN1: x -> h1, + degree histogram (one dispatch; deg zeroed above)
    ln_hist<<<dim3(lnBlocks + histBlocks), b256, 0, stream>>>(
        x, g1, be1, h1, n, eidx, ideg, E_, lnBlocks);
    // QKV: one dispatch, col-blocks -> Q|K|V buffers (obStride = nf)
    gemm_lds<true, false, false, 1><<<dim3(rb, 3), b256, 0, stream>>>(
        h1, 128, Wt, 128, bqkv, Qb, 128, nf, nullptr, 0, n, nullptr, nullptr, nullptr);
    // CSR: alloc then scatter
    alloc_kernel<<<nGrid, b256, 0, stream>>>(ideg, istart, icursor, counter, n);
    scatter_kernel<<<eGrid, b256, 0, stream>>>(eidx, icursor, esrc, E_);
    // fused attention + aggregation into ag
    attn_aggr_kernel<<<n4Grid, b256, 0, stream>>>(Qb, Kb, Vb, istart, ideg, esrc, ag, n);
    // Wo + residual + fused LN2: x2 -> d_out (fp32), h2 (bf16, overlays r2)
    gemm_lds<false, false, true, 1><<<dim3(rb, 1), b256, 0, stream>>>(
        ag, 128, Wt + 49152, 128, bo, out, 128, 0, x, 128, n, g2, be2, h2);
    // FFN1: h2 @ W1 + b1, ReLU -> u [N,512] bf16 (overlays h1|Q|K|V, all dead)
    gemm_lds<true, true, false, 1><<<dim3(rb, 4), b256, 0, stream>>>(
        h2, 128, Wt + 65536, 128, b1, uB, 512, 128, nullptr, 0, n, nullptr, nullptr, nullptr);
    // FFN2: u @ W2 + b2 + x2 -> d_out (K=512 -> 4 k-tiles)
    gemm_lds<false, false, false, 4><<<dim3(rb, 1), b256, 0, stream>>>(
        uB, 512, Wt + 131072, 512, b2, out, 128, 0, out, 128, n, nullptr, nullptr, nullptr);
}

// Round 11
// 456.655 us; speedup vs baseline: 1.2937x; 1.0019x over previous
//
#include <hip/hip_runtime.h>
#include <hip/hip_bf16.h>

#define C_DIM 128
#define EPS_LN 1e-5f

typedef short bf16x8 __attribute__((ext_vector_type(8)));
typedef float f32x4  __attribute__((ext_vector_type(4)));
typedef __hip_bfloat16 bf16;

__device__ inline unsigned short f2bu(float f) {
    bf16 h = __float2bfloat16(f);
    return *reinterpret_cast<unsigned short*>(&h);
}
__device__ inline float blo(unsigned int u) { return __uint_as_float(u << 16); }
__device__ inline float bhi(unsigned int u) { return __uint_as_float(u & 0xffff0000u); }
__device__ inline ushort4 pack4(float a, float b, float c, float d) {
    ushort4 r; r.x = f2bu(a); r.y = f2bu(b); r.z = f2bu(c); r.w = f2bu(d); return r;
}

// async global->LDS DMA, 16B per lane. LDS dest is WAVE-UNIFORM base;
// HW writes lane l's 16B at base + l*16. Global src is per-lane.
__device__ inline void async_copy16(const bf16* g, bf16* s) {
    __builtin_amdgcn_global_load_lds(
        (const __attribute__((address_space(1))) unsigned int*)g,
        (__attribute__((address_space(3))) unsigned int*)s,
        16, 0, 0);
}

// -------- weights convert+transpose + bias pack + deg zero, ONE dispatch ---
// Blocks [0,770): dst (bf16): Wqt|Wkt|Wvt|Wot (4x 128*128) | Wt1[512][128] |
// Wt2[128][512], then packed fp32 bqkv[384]. Blocks [770,...): zero deg[n+1].
__global__ __launch_bounds__(256) void wconv_zero(
    const float* __restrict__ Wq, const float* __restrict__ Wk,
    const float* __restrict__ Wv, const float* __restrict__ Wo,
    const float* __restrict__ W1, const float* __restrict__ W2,
    const float* __restrict__ bq, const float* __restrict__ bk,
    const float* __restrict__ bv, bf16* __restrict__ dst,
    int* __restrict__ deg, int nn1) {
    if (blockIdx.x >= 770) {
        int i = (blockIdx.x - 770) * 256 + threadIdx.x;
        if (i < nn1) deg[i] = 0;
        return;
    }
    int idx = blockIdx.x * 256 + threadIdx.x;
    if (idx < 65536) {                       // four 128x128 weights
        int r = idx >> 14, o = idx & 16383;
        int k = o >> 7, nn = o & 127;
        const float* W = (r == 0) ? Wq : (r == 1) ? Wk : (r == 2) ? Wv : Wo;
        dst[(r << 14) + nn * 128 + k] = __float2bfloat16(W[o]);
    } else if (idx < 131072) {               // W1 [128,512] -> Wt1[n][k]
        int o = idx - 65536;
        int k = o >> 9, nn = o & 511;
        dst[65536 + nn * 128 + k] = __float2bfloat16(W1[o]);
    } else if (idx < 196608) {               // W2 [512,128] -> Wt2[n][k]
        int o = idx - 131072;
        int k = o >> 7, nn = o & 127;
        dst[131072 + nn * 512 + k] = __float2bfloat16(W2[o]);
    } else if (idx < 196992) {               // packed bqkv[384] fp32
        int j = idx - 196608;
        int grp = j >> 7, col = j & 127;
        const float* bp = (grp == 0) ? bq : (grp == 1) ? bk : bv;
        ((float*)(dst + 196608))[j] = bp[col];
    }
}

// -------- LayerNorm fp32 -> bf16 (blocks < lnBlocks) + degree histogram ----
// hist part requires deg zeroed: guaranteed by preceding wconv_zero dispatch.
__global__ __launch_bounds__(256) void ln_hist(
    const float* __restrict__ x, const float* __restrict__ g,
    const float* __restrict__ b, bf16* __restrict__ out, int n,
    const int* __restrict__ eidx, int* __restrict__ deg, int E_, int lnBlocks) {
    if (blockIdx.x >= lnBlocks) {
        int e = (blockIdx.x - lnBlocks) * 256 + threadIdx.x;
        if (e < E_) atomicAdd(&deg[eidx[E_ + e]], 1);
        return;
    }
    int wave = threadIdx.x >> 6;
    int lane = threadIdx.x & 63;
    int row = blockIdx.x * 4 + wave;
    if (row >= n) return;
    float2 v = ((const float2*)(x + (size_t)row * C_DIM))[lane];
    float s  = v.x + v.y;
    float ss = v.x * v.x + v.y * v.y;
    #pragma unroll
    for (int o = 1; o < 64; o <<= 1) {
        s  += __shfl_xor(s, o);
        ss += __shfl_xor(ss, o);
    }
    float mu  = s * (1.0f / C_DIM);
    float var = ss * (1.0f / C_DIM) - mu * mu;
    float rs  = rsqrtf(var + EPS_LN);
    float2 gg = ((const float2*)g)[lane];
    float2 bb = ((const float2*)b)[lane];
    __hip_bfloat162 o2;
    o2.x = __float2bfloat16((v.x - mu) * rs * gg.x + bb.x);
    o2.y = __float2bfloat16((v.y - mu) * rs * gg.y + bb.y);
    ((__hip_bfloat162*)(out + (size_t)row * C_DIM))[lane] = o2;
}

// ---------------- LDS-staged MFMA GEMM (global_load_lds + XOR swizzle) -----
// Round-11: 512-thread / 8-wave blocks at the SAME 64KB LDS + 2 blocks/CU
// -> 16 waves/CU (was 8). Doubles the work available to overlap another
// block's vmcnt(0)+barrier drain, with identical traffic and per-block
// staging volume. (r9's more-blocks was net-zero: shorter phases; this
// keeps phase structure, adds waves.) Each wave: 16 rows x 128 cols,
// acc[8] f32x4, 4 A-calls + 4 B-calls staging rows w*16+i*4+rsub.
// A [M,lda] bf16 row-major; Bt [Ncols][Kfull] bf16 (row = output col).
// Staging: async_copy16, wave-uniform LDS base (linear [128][128]), per-lane
// global src pre-swizzled: LDS slot s of row r holds global slot s^(r&7).
// Reads use ((ks*4+q)^(m&7))<<3 -> bank-uniform (2 lanes/bank, free).
// Tail: clamp source row to M-1 (garbage lands only in C rows >= M, masked).
// Locked by measurement: A-direct (r3: HBM overfetch), NCB (r7: parallelism
// collapse), B-direct (r8: latency not hidden), BK=64 (r9: neutral).
// Operand-swapped mfma(bf, af, acc): lane(m,q) reg r = C[row0+..+m][ct*16+q*4+r].
template<bool OUTBF16, bool RELU, bool FUSE_LN, int KSTEPS>
__global__ __launch_bounds__(512) void gemm_lds(
    const bf16* __restrict__ A, int lda,
    const bf16* __restrict__ Bt, int Kfull,
    const float* __restrict__ biasBase,
    void* __restrict__ Cd, int ldc, size_t obStride,
    const float* __restrict__ resid, int ldres,
    int M,
    const float* __restrict__ g, const float* __restrict__ be,
    bf16* __restrict__ h2) {
    __shared__ bf16 As[128][128];
    __shared__ bf16 Bs[128][128];
    int tid  = threadIdx.x;
    int lane = tid & 63;
    int w    = tid >> 6;              // 0..7
    int m = lane & 15, q = lane >> 4;
    int row0 = blockIdx.x * 128;
    const bf16* Bbase = Bt + (size_t)blockIdx.y * 128 * Kfull;

    f32x4 acc[8];
    #pragma unroll
    for (int ct = 0; ct < 8; ct++) acc[ct] = (f32x4){0.f, 0.f, 0.f, 0.f};

    int rsub  = lane >> 4;      // 0..3: this lane's dest row within a 4-row DMA call
    int cslot = lane & 15;      // this lane's 16B slot within the row

    for (int kt = 0; kt < KSTEPS; kt++) {
        // stage A+B tiles [128][128]: each wave 16 rows via 4+4 DMA calls
        #pragma unroll
        for (int i = 0; i < 4; i++) {
            int arow = w * 16 + i * 4 + rsub;                 // dest row 0..127
            int scol = (cslot ^ (arow & 7)) << 3;             // swizzled src slot (elems)
            int garow = row0 + arow;
            if (garow > M - 1) garow = M - 1;                 // tail clamp
            async_copy16(A + (size_t)garow * lda + kt * 128 + scol, &As[w * 16 + i * 4][0]);
            async_copy16(Bbase + (size_t)arow * Kfull + kt * 128 + scol, &Bs[w * 16 + i * 4][0]);
        }
        __syncthreads();
        #pragma unroll
        for (int ks = 0; ks < 4; ks++) {
            int sofs = ((ks * 4 + q) ^ (m & 7)) << 3;         // swizzled read offset
            bf16x8 af = *(const bf16x8*)&As[w * 16 + m][sofs];
            #pragma unroll
            for (int ct = 0; ct < 8; ct++) {
                bf16x8 bf = *(const bf16x8*)&Bs[ct * 16 + m][sofs];
                acc[ct] = __builtin_amdgcn_mfma_f32_16x16x32_bf16(bf, af, acc[ct], 0, 0, 0);
            }
        }
        if (kt + 1 < KSTEPS) __syncthreads();
    }

    // ---- epilogue: one 16-row tile per wave ----
    {
        int row = row0 + w * 16 + m;
        bool valid = row < M;
        float vals[8][4];
        #pragma unroll
        for (int ct = 0; ct < 8; ct++) {
            int col = ct * 16 + q * 4;
            float4 bv = make_float4(0.f, 0.f, 0.f, 0.f);
            if (biasBase) bv = *(const float4*)(biasBase + blockIdx.y * 128 + col);
            float4 rv = make_float4(0.f, 0.f, 0.f, 0.f);
            if (resid && valid) rv = *(const float4*)(resid + (size_t)row * ldres + col);
            vals[ct][0] = acc[ct][0] + bv.x + rv.x;
            vals[ct][1] = acc[ct][1] + bv.y + rv.y;
            vals[ct][2] = acc[ct][2] + bv.z + rv.z;
            vals[ct][3] = acc[ct][3] + bv.w + rv.w;
        }
        if (FUSE_LN) {
            // row spans lanes {m, m+16, m+32, m+48}: reduce over q via xor 16,32
            float s1 = 0.f, s2 = 0.f;
            #pragma unroll
            for (int ct = 0; ct < 8; ct++)
                #pragma unroll
                for (int r = 0; r < 4; r++) { s1 += vals[ct][r]; s2 += vals[ct][r] * vals[ct][r]; }
            s1 += __shfl_xor(s1, 16); s1 += __shfl_xor(s1, 32);
            s2 += __shfl_xor(s2, 16); s2 += __shfl_xor(s2, 32);
            float mu  = s1 * (1.0f / 128.f);
            float var = s2 * (1.0f / 128.f) - mu * mu;
            float rs  = rsqrtf(var + EPS_LN);
            if (valid) {
                #pragma unroll
                for (int ct = 0; ct < 8; ct++) {
                    int col = ct * 16 + q * 4;
                    *(float4*)((float*)Cd + (size_t)row * ldc + col) =
                        make_float4(vals[ct][0], vals[ct][1], vals[ct][2], vals[ct][3]);
                    float4 gg = *(const float4*)(g + col);
                    float4 bb = *(const float4*)(be + col);
                    *(ushort4*)(h2 + (size_t)row * 128 + col) =
                        pack4((vals[ct][0] - mu) * rs * gg.x + bb.x,
                              (vals[ct][1] - mu) * rs * gg.y + bb.y,
                              (vals[ct][2] - mu) * rs * gg.z + bb.z,
                              (vals[ct][3] - mu) * rs * gg.w + bb.w);
                }
            }
        } else if (valid) {
            #pragma unroll
            for (int ct = 0; ct < 8; ct++) {
                int col = ct * 16 + q * 4;
                float v0 = vals[ct][0], v1 = vals[ct][1];
                float v2 = vals[ct][2], v3 = vals[ct][3];
                if (RELU) {
                    v0 = fmaxf(v0, 0.f); v1 = fmaxf(v1, 0.f);
                    v2 = fmaxf(v2, 0.f); v3 = fmaxf(v3, 0.f);
                }
                if (OUTBF16) {
                    *(ushort4*)((bf16*)Cd + blockIdx.y * obStride + (size_t)row * ldc + col) =
                        pack4(v0, v1, v2, v3);
                } else {
                    *(float4*)((float*)Cd + blockIdx.y * obStride + (size_t)row * ldc + col) =
                        make_float4(v0, v1, v2, v3);
                }
            }
        }
    }
}

// ---------------- CSR build (alloc + scatter; hist merged into ln_hist) ----
__global__ __launch_bounds__(256) void alloc_kernel(
    const int* __restrict__ deg, int* __restrict__ start,
    int* __restrict__ cursor, int* __restrict__ counter, int n) {
    int i = blockIdx.x * 256 + threadIdx.x;
    if (i >= n) return;
    int d = deg[i];
    int s = atomicAdd(counter, d);
    start[i] = s;
    cursor[i] = s;
}

__global__ __launch_bounds__(256) void scatter_kernel(
    const int* __restrict__ eidx, int* __restrict__ cursor,
    int* __restrict__ esrc, int E_) {
    int e = blockIdx.x * 256 + threadIdx.x;
    if (e >= E_) return;
    int src = eidx[e];
    int dst = eidx[E_ + e];
    int pos = atomicAdd(&cursor[dst], 1);
    esrc[pos] = src;
}

// ---------- fused attention + aggregation: one wave per node ---------------
// (round-6 state: K + all-8-V loads issued together -> one exposed gather
// round; predicated phase 2, no branches; exp2f folded scale; fast div.)
__device__ inline float dot8f(uint4 a, uint4 b) {
    return blo(a.x) * blo(b.x) + bhi(a.x) * bhi(b.x)
         + blo(a.y) * blo(b.y) + bhi(a.y) * bhi(b.y)
         + blo(a.z) * blo(b.z) + bhi(a.z) * bhi(b.z)
         + blo(a.w) * blo(b.w) + bhi(a.w) * bhi(b.w);
}

__global__ __launch_bounds__(256) void attn_aggr_kernel(
    const bf16* __restrict__ Q, const bf16* __restrict__ K,
    const bf16* __restrict__ V,
    const int* __restrict__ start, const int* __restrict__ deg,
    const int* __restrict__ esrc, bf16* __restrict__ ag, int n) {
    int wave = threadIdx.x >> 6;
    int lane = threadIdx.x & 63;
    int i = blockIdx.x * 4 + wave;
    if (i >= n) return;
    int s = start[i], d = deg[i];
    int end = s + d;
    int g = lane >> 3;          // edge slot within 8-batch (== head in phase 2)
    int l = lane & 7;           // head owned in phase 1
    const uint4* qh = (const uint4*)(Q + (size_t)i * 128 + l * 16);
    uint4 q0 = qh[0], q1 = qh[1];
    const float SC = 0.25f * 1.44269504089f;   // /sqrt(16) * log2(e)
    float ax = 0.f, ay = 0.f;
    for (int j = s; j < end; j += 8) {
        int eg = j + g;
        int se = esrc[eg < end ? eg : end - 1];
        const uint4* kh = (const uint4*)(K + (size_t)se * 128 + l * 16);
        uint4 k0 = kh[0], k1 = kh[1];
        unsigned vu[8];
        #pragma unroll
        for (int e = 0; e < 8; e++) {
            int sv = __shfl(se, e * 8);
            vu[e] = ((const unsigned*)(V + (size_t)sv * 128))[lane];
        }
        float p = (dot8f(q0, k0) + dot8f(q1, k1)) * SC;
        float mx = fmaxf(p, __shfl_xor(p, 1));
        mx = fmaxf(mx, __shfl_xor(mx, 2));
        mx = fmaxf(mx, __shfl_xor(mx, 4));
        float ex = exp2f(p - mx);
        float t = ex + __shfl_xor(ex, 1);
        t += __shfl_xor(t, 2);
        t += __shfl_xor(t, 4);
        float wgt = __fdividef(ex, t);
        #pragma unroll
        for (int e = 0; e < 8; e++) {
            float we = (j + e < end) ? __shfl(wgt, e * 8 + g) : 0.f;
            ax += we * blo(vu[e]);
            ay += we * bhi(vu[e]);
        }
    }
    __hip_bfloat162 o2;
    o2.x = __float2bfloat16(ax);
    o2.y = __float2bfloat16(ay);
    ((__hip_bfloat162*)(ag + (size_t)i * 128))[lane] = o2;
}

extern "C" void kernel_launch(void* const* d_in, const int* in_sizes, int n_in,
                              void* d_out, int out_size, void* d_ws, size_t ws_size,
                              hipStream_t stream) {
    const float* x   = (const float*)d_in[0];
    const int*  eidx = (const int*)d_in[1];
    const float* Wq = (const float*)d_in[2];  const float* bq = (const float*)d_in[3];
    const float* Wk = (const float*)d_in[4];  const float* bk = (const float*)d_in[5];
    const float* Wv = (const float*)d_in[6];  const float* bv = (const float*)d_in[7];
    const float* Wo = (const float*)d_in[8];  const float* bo = (const float*)d_in[9];
    const float* W1 = (const float*)d_in[10]; const float* b1 = (const float*)d_in[11];
    const float* W2 = (const float*)d_in[12]; const float* b2 = (const float*)d_in[13];
    const float* g1 = (const float*)d_in[14]; const float* be1 = (const float*)d_in[15];
    const float* g2 = (const float*)d_in[16]; const float* be2 = (const float*)d_in[17];
    float* out = (float*)d_out;

    int n  = in_sizes[0] / C_DIM;   // 100000
    int E_ = in_sizes[1] / 2;       // 600000
    size_t nf = (size_t)n * 128;

    // ---- workspace ----
    bf16* Wt    = (bf16*)d_ws;                // 196608 bf16 transposed weights
    float* bqkv = (float*)(Wt + 196608);      // packed [bq|bk|bv]
    bf16* reg0  = (bf16*)(bqkv + 384);        // 4*nf: h1|Q|K|V ; u overlays all
    bf16* h1 = reg0;
    bf16* Qb = reg0 + nf;
    bf16* Kb = reg0 + 2 * nf;
    bf16* Vb = reg0 + 3 * nf;
    bf16* uB = reg0;                          // [N,512] bf16 (FFN intermediate)
    bf16* ag = reg0 + 4 * nf;                 // [N,128]
    char* r2 = (char*)(ag + nf);              // union region
    int*  esrc   = (int*)r2;                  // [E] CSR-ordered source ids
    int*  ideg   = esrc + E_;
    int*  counter = ideg + n;
    int*  istart  = ideg + n + 1;
    int*  icursor = istart + n;
    bf16* h2 = (bf16*)r2;                     // overlays esrc/CSR after attn_aggr

    dim3 b256(256);
    dim3 b512(512);
    int lnBlocks = (n + 3) / 4;               // 25000
    int histBlocks = (E_ + 255) / 256;        // 2344
    int zeroBlocks = (n + 1 + 255) / 256;     // 391
    int rb = (n + 127) / 128;                 // 782
    dim3 eGrid((E_ + 255) / 256);
    dim3 nGrid((n + 255) / 256);
    dim3 n4Grid((n + 3) / 4);

    // weights -> bf16 transposed + packed bqkv + zero deg (one dispatch)
    wconv_zero<<<dim3(770 + zeroBlocks), b256, 0, stream>>>(
        Wq, Wk, Wv, Wo, W1, W2, bq, bk, bv, Wt, ideg, n + 1);
    // LN1: x -> h1, + degree histogram (one dispatch; deg zeroed above)
    ln_hist<<<dim3(lnBlocks + histBlocks), b256, 0, stream>>>(
        x, g1, be1, h1, n, eidx, ideg, E_, lnBlocks);
    // QKV: one dispatch, col-blocks -> Q|K|V buffers (obStride = nf)
    gemm_lds<true, false, false, 1><<<dim3(rb, 3), b512, 0, stream>>>(
        h1, 128, Wt, 128, bqkv, Qb, 128, nf, nullptr, 0, n, nullptr, nullptr, nullptr);
    // CSR: alloc then scatter
    alloc_kernel<<<nGrid, b256, 0, stream>>>(ideg, istart, icursor, counter, n);
    scatter_kernel<<<eGrid, b256, 0, stream>>>(eidx, icursor, esrc, E_);
    // fused attention + aggregation into ag
    attn_aggr_kernel<<<n4Grid, b256, 0, stream>>>(Qb, Kb, Vb, istart, ideg, esrc, ag, n);
    // Wo + residual + fused LN2: x2 -> d_out (fp32), h2 (bf16, overlays r2)
    gemm_lds<false, false, true, 1><<<dim3(rb, 1), b512, 0, stream>>>(
        ag, 128, Wt + 49152, 128, bo, out, 128, 0, x, 128, n, g2, be2, h2);
    // FFN1: h2 @ W1 + b1, ReLU -> u [N,512] bf16 (overlays h1|Q|K|V, all dead)
    gemm_lds<true, true, false, 1><<<dim3(rb, 4), b512, 0, stream>>>(
        h2, 128, Wt + 65536, 128, b1, uB, 512, 128, nullptr, 0, n, nullptr, nullptr, nullptr);
    // FFN2: u @ W2 + b2 + x2 -> d_out (K=512 -> 4 k-tiles)
    gemm_lds<false, false, false, 4><<<dim3(rb, 1), b512, 0, stream>>>(
        uB, 512, Wt + 131072, 512, b2, out, 128, 0, out, 128, n, nullptr, nullptr, nullptr);
}

// Round 12
// 448.860 us; speedup vs baseline: 1.3162x; 1.0174x over previous
//
#include <hip/hip_runtime.h>
#include <hip/hip_bf16.h>

#define C_DIM 128
#define EPS_LN 1e-5f

typedef short bf16x8 __attribute__((ext_vector_type(8)));
typedef float f32x4  __attribute__((ext_vector_type(4)));
typedef __hip_bfloat16 bf16;

__device__ inline unsigned short f2bu(float f) {
    bf16 h = __float2bfloat16(f);
    return *reinterpret_cast<unsigned short*>(&h);
}
__device__ inline float blo(unsigned int u) { return __uint_as_float(u << 16); }
__device__ inline float bhi(unsigned int u) { return __uint_as_float(u & 0xffff0000u); }
__device__ inline ushort4 pack4(float a, float b, float c, float d) {
    ushort4 r; r.x = f2bu(a); r.y = f2bu(b); r.z = f2bu(c); r.w = f2bu(d); return r;
}

// async global->LDS DMA, 16B per lane. LDS dest is WAVE-UNIFORM base;
// HW writes lane l's 16B at base + l*16. Global src is per-lane.
__device__ inline void async_copy16(const bf16* g, bf16* s) {
    __builtin_amdgcn_global_load_lds(
        (const __attribute__((address_space(1))) unsigned int*)g,
        (__attribute__((address_space(3))) unsigned int*)s,
        16, 0, 0);
}

// -------- weights convert+transpose + bias pack + deg zero, ONE dispatch ---
// Blocks [0,770): dst (bf16): Wqt|Wkt|Wvt|Wot (4x 128*128) | Wt1[512][128] |
// Wt2[128][512], then packed fp32 bqkv[384]. Blocks [770,...): zero deg[n+1].
__global__ __launch_bounds__(256) void wconv_zero(
    const float* __restrict__ Wq, const float* __restrict__ Wk,
    const float* __restrict__ Wv, const float* __restrict__ Wo,
    const float* __restrict__ W1, const float* __restrict__ W2,
    const float* __restrict__ bq, const float* __restrict__ bk,
    const float* __restrict__ bv, bf16* __restrict__ dst,
    int* __restrict__ deg, int nn1) {
    if (blockIdx.x >= 770) {
        int i = (blockIdx.x - 770) * 256 + threadIdx.x;
        if (i < nn1) deg[i] = 0;
        return;
    }
    int idx = blockIdx.x * 256 + threadIdx.x;
    if (idx < 65536) {                       // four 128x128 weights
        int r = idx >> 14, o = idx & 16383;
        int k = o >> 7, nn = o & 127;
        const float* W = (r == 0) ? Wq : (r == 1) ? Wk : (r == 2) ? Wv : Wo;
        dst[(r << 14) + nn * 128 + k] = __float2bfloat16(W[o]);
    } else if (idx < 131072) {               // W1 [128,512] -> Wt1[n][k]
        int o = idx - 65536;
        int k = o >> 9, nn = o & 511;
        dst[65536 + nn * 128 + k] = __float2bfloat16(W1[o]);
    } else if (idx < 196608) {               // W2 [512,128] -> Wt2[n][k]
        int o = idx - 131072;
        int k = o >> 7, nn = o & 127;
        dst[131072 + nn * 512 + k] = __float2bfloat16(W2[o]);
    } else if (idx < 196992) {               // packed bqkv[384] fp32
        int j = idx - 196608;
        int grp = j >> 7, col = j & 127;
        const float* bp = (grp == 0) ? bq : (grp == 1) ? bk : bv;
        ((float*)(dst + 196608))[j] = bp[col];
    }
}

// -------- LayerNorm fp32 -> bf16 (blocks < lnBlocks) + degree histogram ----
// hist part requires deg zeroed: guaranteed by preceding wconv_zero dispatch.
__global__ __launch_bounds__(256) void ln_hist(
    const float* __restrict__ x, const float* __restrict__ g,
    const float* __restrict__ b, bf16* __restrict__ out, int n,
    const int* __restrict__ eidx, int* __restrict__ deg, int E_, int lnBlocks) {
    if (blockIdx.x >= lnBlocks) {
        int e = (blockIdx.x - lnBlocks) * 256 + threadIdx.x;
        if (e < E_) atomicAdd(&deg[eidx[E_ + e]], 1);
        return;
    }
    int wave = threadIdx.x >> 6;
    int lane = threadIdx.x & 63;
    int row = blockIdx.x * 4 + wave;
    if (row >= n) return;
    float2 v = ((const float2*)(x + (size_t)row * C_DIM))[lane];
    float s  = v.x + v.y;
    float ss = v.x * v.x + v.y * v.y;
    #pragma unroll
    for (int o = 1; o < 64; o <<= 1) {
        s  += __shfl_xor(s, o);
        ss += __shfl_xor(ss, o);
    }
    float mu  = s * (1.0f / C_DIM);
    float var = ss * (1.0f / C_DIM) - mu * mu;
    float rs  = rsqrtf(var + EPS_LN);
    float2 gg = ((const float2*)g)[lane];
    float2 bb = ((const float2*)b)[lane];
    __hip_bfloat162 o2;
    o2.x = __float2bfloat16((v.x - mu) * rs * gg.x + bb.x);
    o2.y = __float2bfloat16((v.y - mu) * rs * gg.y + bb.y);
    ((__hip_bfloat162*)(out + (size_t)row * C_DIM))[lane] = o2;
}

// ---------------- LDS-staged MFMA GEMM (global_load_lds + XOR swizzle) -----
// 512-thread / 8-wave blocks, 64KB LDS, 2 blocks/CU (r11; equal to r6's
// 256-thread within noise). Each wave: 16 rows x 128 cols, acc[8] f32x4.
// A [M,lda] bf16 row-major; Bt [Ncols][Kfull] bf16 (row = output col).
// Staging: async_copy16, wave-uniform LDS base (linear [128][128]), per-lane
// global src pre-swizzled: LDS slot s of row r holds global slot s^(r&7).
// Reads use ((ks*4+q)^(m&7))<<3 -> bank-uniform (2 lanes/bank, free).
// Tail: clamp source row to M-1 (garbage lands only in C rows >= M, masked).
// Locked by measurement: A-direct (r3: HBM overfetch), NCB (r7: parallelism
// collapse), B-direct (r8: latency not hidden), BK=64 (r9: neutral),
// 8-wave (r11: neutral). This family is at its floor.
// Operand-swapped mfma(bf, af, acc): lane(m,q) reg r = C[row0+..+m][ct*16+q*4+r].
template<bool OUTBF16, bool RELU, bool FUSE_LN, int KSTEPS>
__global__ __launch_bounds__(512) void gemm_lds(
    const bf16* __restrict__ A, int lda,
    const bf16* __restrict__ Bt, int Kfull,
    const float* __restrict__ biasBase,
    void* __restrict__ Cd, int ldc, size_t obStride,
    const float* __restrict__ resid, int ldres,
    int M,
    const float* __restrict__ g, const float* __restrict__ be,
    bf16* __restrict__ h2) {
    __shared__ bf16 As[128][128];
    __shared__ bf16 Bs[128][128];
    int tid  = threadIdx.x;
    int lane = tid & 63;
    int w    = tid >> 6;              // 0..7
    int m = lane & 15, q = lane >> 4;
    int row0 = blockIdx.x * 128;
    const bf16* Bbase = Bt + (size_t)blockIdx.y * 128 * Kfull;

    f32x4 acc[8];
    #pragma unroll
    for (int ct = 0; ct < 8; ct++) acc[ct] = (f32x4){0.f, 0.f, 0.f, 0.f};

    int rsub  = lane >> 4;      // 0..3: this lane's dest row within a 4-row DMA call
    int cslot = lane & 15;      // this lane's 16B slot within the row

    for (int kt = 0; kt < KSTEPS; kt++) {
        // stage A+B tiles [128][128]: each wave 16 rows via 4+4 DMA calls
        #pragma unroll
        for (int i = 0; i < 4; i++) {
            int arow = w * 16 + i * 4 + rsub;                 // dest row 0..127
            int scol = (cslot ^ (arow & 7)) << 3;             // swizzled src slot (elems)
            int garow = row0 + arow;
            if (garow > M - 1) garow = M - 1;                 // tail clamp
            async_copy16(A + (size_t)garow * lda + kt * 128 + scol, &As[w * 16 + i * 4][0]);
            async_copy16(Bbase + (size_t)arow * Kfull + kt * 128 + scol, &Bs[w * 16 + i * 4][0]);
        }
        __syncthreads();
        #pragma unroll
        for (int ks = 0; ks < 4; ks++) {
            int sofs = ((ks * 4 + q) ^ (m & 7)) << 3;         // swizzled read offset
            bf16x8 af = *(const bf16x8*)&As[w * 16 + m][sofs];
            #pragma unroll
            for (int ct = 0; ct < 8; ct++) {
                bf16x8 bf = *(const bf16x8*)&Bs[ct * 16 + m][sofs];
                acc[ct] = __builtin_amdgcn_mfma_f32_16x16x32_bf16(bf, af, acc[ct], 0, 0, 0);
            }
        }
        if (kt + 1 < KSTEPS) __syncthreads();
    }

    // ---- epilogue: one 16-row tile per wave ----
    {
        int row = row0 + w * 16 + m;
        bool valid = row < M;
        float vals[8][4];
        #pragma unroll
        for (int ct = 0; ct < 8; ct++) {
            int col = ct * 16 + q * 4;
            float4 bv = make_float4(0.f, 0.f, 0.f, 0.f);
            if (biasBase) bv = *(const float4*)(biasBase + blockIdx.y * 128 + col);
            float4 rv = make_float4(0.f, 0.f, 0.f, 0.f);
            if (resid && valid) rv = *(const float4*)(resid + (size_t)row * ldres + col);
            vals[ct][0] = acc[ct][0] + bv.x + rv.x;
            vals[ct][1] = acc[ct][1] + bv.y + rv.y;
            vals[ct][2] = acc[ct][2] + bv.z + rv.z;
            vals[ct][3] = acc[ct][3] + bv.w + rv.w;
        }
        if (FUSE_LN) {
            // row spans lanes {m, m+16, m+32, m+48}: reduce over q via xor 16,32
            float s1 = 0.f, s2 = 0.f;
            #pragma unroll
            for (int ct = 0; ct < 8; ct++)
                #pragma unroll
                for (int r = 0; r < 4; r++) { s1 += vals[ct][r]; s2 += vals[ct][r] * vals[ct][r]; }
            s1 += __shfl_xor(s1, 16); s1 += __shfl_xor(s1, 32);
            s2 += __shfl_xor(s2, 16); s2 += __shfl_xor(s2, 32);
            float mu  = s1 * (1.0f / 128.f);
            float var = s2 * (1.0f / 128.f) - mu * mu;
            float rs  = rsqrtf(var + EPS_LN);
            if (valid) {
                #pragma unroll
                for (int ct = 0; ct < 8; ct++) {
                    int col = ct * 16 + q * 4;
                    *(float4*)((float*)Cd + (size_t)row * ldc + col) =
                        make_float4(vals[ct][0], vals[ct][1], vals[ct][2], vals[ct][3]);
                    float4 gg = *(const float4*)(g + col);
                    float4 bb = *(const float4*)(be + col);
                    *(ushort4*)(h2 + (size_t)row * 128 + col) =
                        pack4((vals[ct][0] - mu) * rs * gg.x + bb.x,
                              (vals[ct][1] - mu) * rs * gg.y + bb.y,
                              (vals[ct][2] - mu) * rs * gg.z + bb.z,
                              (vals[ct][3] - mu) * rs * gg.w + bb.w);
                }
            }
        } else if (valid) {
            #pragma unroll
            for (int ct = 0; ct < 8; ct++) {
                int col = ct * 16 + q * 4;
                float v0 = vals[ct][0], v1 = vals[ct][1];
                float v2 = vals[ct][2], v3 = vals[ct][3];
                if (RELU) {
                    v0 = fmaxf(v0, 0.f); v1 = fmaxf(v1, 0.f);
                    v2 = fmaxf(v2, 0.f); v3 = fmaxf(v3, 0.f);
                }
                if (OUTBF16) {
                    *(ushort4*)((bf16*)Cd + blockIdx.y * obStride + (size_t)row * ldc + col) =
                        pack4(v0, v1, v2, v3);
                } else {
                    *(float4*)((float*)Cd + blockIdx.y * obStride + (size_t)row * ldc + col) =
                        make_float4(v0, v1, v2, v3);
                }
            }
        }
    }
}

// ---------------- CSR build (alloc + scatter; hist merged into ln_hist) ----
__global__ __launch_bounds__(256) void alloc_kernel(
    const int* __restrict__ deg, int* __restrict__ start,
    int* __restrict__ cursor, int* __restrict__ counter, int n) {
    int i = blockIdx.x * 256 + threadIdx.x;
    if (i >= n) return;
    int d = deg[i];
    int s = atomicAdd(counter, d);
    start[i] = s;
    cursor[i] = s;
}

__global__ __launch_bounds__(256) void scatter_kernel(
    const int* __restrict__ eidx, int* __restrict__ cursor,
    int* __restrict__ esrc, int E_) {
    int e = blockIdx.x * 256 + threadIdx.x;
    if (e >= E_) return;
    int src = eidx[e];
    int dst = eidx[E_ + e];
    int pos = atomicAdd(&cursor[dst], 1);
    esrc[pos] = src;
}

// ---------- fused attention + aggregation: persistent grid-stride waves ----
// Round-12: one wave = MANY nodes (grid-stride, ~12 nodes/wave at 2048
// blocks). Rationale: with 1 node/wave, block retires on its slowest of 4
// waves; degree ~ Poisson(6) -> E[max of 4] ~ 10.5 vs mean 6 = ~57% wave
// utilization (matches measured Occupancy 42%/VALU 57%). Summing ~12 draws
// per wave shrinks relative spread 0.41 -> 0.12 -> straggler cost collapses.
// All waves resident (8 blocks/CU, LDS=0, VGPR 44) -> zero dispatch churn;
// node t+1's start/deg/Q loads issue under node t's tail latency.
// Per-node math unchanged (round-6 state: K + all-8-V loads issued together,
// predicated phase 2, exp2f folded scale, fast div).
__device__ inline float dot8f(uint4 a, uint4 b) {
    return blo(a.x) * blo(b.x) + bhi(a.x) * bhi(b.x)
         + blo(a.y) * blo(b.y) + bhi(a.y) * bhi(b.y)
         + blo(a.z) * blo(b.z) + bhi(a.z) * bhi(b.z)
         + blo(a.w) * blo(b.w) + bhi(a.w) * bhi(b.w);
}

__global__ __launch_bounds__(256) void attn_aggr_kernel(
    const bf16* __restrict__ Q, const bf16* __restrict__ K,
    const bf16* __restrict__ V,
    const int* __restrict__ start, const int* __restrict__ deg,
    const int* __restrict__ esrc, bf16* __restrict__ ag, int n) {
    int wave = threadIdx.x >> 6;
    int lane = threadIdx.x & 63;
    int totalWaves = gridDim.x * 4;
    int g = lane >> 3;          // edge slot within 8-batch (== head in phase 2)
    int l = lane & 7;           // head owned in phase 1
    const float SC = 0.25f * 1.44269504089f;   // /sqrt(16) * log2(e)
    for (int i = blockIdx.x * 4 + wave; i < n; i += totalWaves) {
        int s = start[i], d = deg[i];
        int end = s + d;
        const uint4* qh = (const uint4*)(Q + (size_t)i * 128 + l * 16);
        uint4 q0 = qh[0], q1 = qh[1];
        float ax = 0.f, ay = 0.f;
        for (int j = s; j < end; j += 8) {
            int eg = j + g;
            int se = esrc[eg < end ? eg : end - 1];
            const uint4* kh = (const uint4*)(K + (size_t)se * 128 + l * 16);
            uint4 k0 = kh[0], k1 = kh[1];
            unsigned vu[8];
            #pragma unroll
            for (int e = 0; e < 8; e++) {
                int sv = __shfl(se, e * 8);
                vu[e] = ((const unsigned*)(V + (size_t)sv * 128))[lane];
            }
            float p = (dot8f(q0, k0) + dot8f(q1, k1)) * SC;
            float mx = fmaxf(p, __shfl_xor(p, 1));
            mx = fmaxf(mx, __shfl_xor(mx, 2));
            mx = fmaxf(mx, __shfl_xor(mx, 4));
            float ex = exp2f(p - mx);
            float t = ex + __shfl_xor(ex, 1);
            t += __shfl_xor(t, 2);
            t += __shfl_xor(t, 4);
            float wgt = __fdividef(ex, t);
            #pragma unroll
            for (int e = 0; e < 8; e++) {
                float we = (j + e < end) ? __shfl(wgt, e * 8 + g) : 0.f;
                ax += we * blo(vu[e]);
                ay += we * bhi(vu[e]);
            }
        }
        __hip_bfloat162 o2;
        o2.x = __float2bfloat16(ax);
        o2.y = __float2bfloat16(ay);
        ((__hip_bfloat162*)(ag + (size_t)i * 128))[lane] = o2;
    }
}

extern "C" void kernel_launch(void* const* d_in, const int* in_sizes, int n_in,
                              void* d_out, int out_size, void* d_ws, size_t ws_size,
                              hipStream_t stream) {
    const float* x   = (const float*)d_in[0];
    const int*  eidx = (const int*)d_in[1];
    const float* Wq = (const float*)d_in[2];  const float* bq = (const float*)d_in[3];
    const float* Wk = (const float*)d_in[4];  const float* bk = (const float*)d_in[5];
    const float* Wv = (const float*)d_in[6];  const float* bv = (const float*)d_in[7];
    const float* Wo = (const float*)d_in[8];  const float* bo = (const float*)d_in[9];
    const float* W1 = (const float*)d_in[10]; const float* b1 = (const float*)d_in[11];
    const float* W2 = (const float*)d_in[12]; const float* b2 = (const float*)d_in[13];
    const float* g1 = (const float*)d_in[14]; const float* be1 = (const float*)d_in[15];
    const float* g2 = (const float*)d_in[16]; const float* be2 = (const float*)d_in[17];
    float* out = (float*)d_out;

    int n  = in_sizes[0] / C_DIM;   // 100000
    int E_ = in_sizes[1] / 2;       // 600000
    size_t nf = (size_t)n * 128;

    // ---- workspace ----
    bf16* Wt    = (bf16*)d_ws;                // 196608 bf16 transposed weights
    float* bqkv = (float*)(Wt + 196608);      // packed [bq|bk|bv]
    bf16* reg0  = (bf16*)(bqkv + 384);        // 4*nf: h1|Q|K|V ; u overlays all
    bf16* h1 = reg0;
    bf16* Qb = reg0 + nf;
    bf16* Kb = reg0 + 2 * nf;
    bf16* Vb = reg0 + 3 * nf;
    bf16* uB = reg0;                          // [N,512] bf16 (FFN intermediate)
    bf16* ag = reg0 + 4 * nf;                 // [N,128]
    char* r2 = (char*)(ag + nf);              // union region
    int*  esrc   = (int*)r2;                  // [E] CSR-ordered source ids
    int*  ideg   = esrc + E_;
    int*  counter = ideg + n;
    int*  istart  = ideg + n + 1;
    int*  icursor = istart + n;
    bf16* h2 = (bf16*)r2;                     // overlays esrc/CSR after attn_aggr

    dim3 b256(256);
    dim3 b512(512);
    int lnBlocks = (n + 3) / 4;               // 25000
    int histBlocks = (E_ + 255) / 256;        // 2344
    int zeroBlocks = (n + 1 + 255) / 256;     // 391
    int rb = (n + 127) / 128;                 // 782
    dim3 eGrid((E_ + 255) / 256);
    dim3 nGrid((n + 255) / 256);

    // weights -> bf16 transposed + packed bqkv + zero deg (one dispatch)
    wconv_zero<<<dim3(770 + zeroBlocks), b256, 0, stream>>>(
        Wq, Wk, Wv, Wo, W1, W2, bq, bk, bv, Wt, ideg, n + 1);
    // LN1: x -> h1, + degree histogram (one dispatch; deg zeroed above)
    ln_hist<<<dim3(lnBlocks + histBlocks), b256, 0, stream>>>(
        x, g1, be1, h1, n, eidx, ideg, E_, lnBlocks);
    // QKV: one dispatch, col-blocks -> Q|K|V buffers (obStride = nf)
    gemm_lds<true, false, false, 1><<<dim3(rb, 3), b512, 0, stream>>>(
        h1, 128, Wt, 128, bqkv, Qb, 128, nf, nullptr, 0, n, nullptr, nullptr, nullptr);
    // CSR: alloc then scatter
    alloc_kernel<<<nGrid, b256, 0, stream>>>(ideg, istart, icursor, counter, n);
    scatter_kernel<<<eGrid, b256, 0, stream>>>(eidx, icursor, esrc, E_);
    // fused attention + aggregation into ag (persistent grid-stride waves)
    attn_aggr_kernel<<<dim3(2048), b256, 0, stream>>>(
        Qb, Kb, Vb, istart, ideg, esrc, ag, n);
    // Wo + residual + fused LN2: x2 -> d_out (fp32), h2 (bf16, overlays r2)
    gemm_lds<false, false, true, 1><<<dim3(rb, 1), b512, 0, stream>>>(
        ag, 128, Wt + 49152, 128, bo, out, 128, 0, x, 128, n, g2, be2, h2);
    // FFN1: h2 @ W1 + b1, ReLU -> u [N,512] bf16 (overlays h1|Q|K|V, all dead)
    gemm_lds<true, true, false, 1><<<dim3(rb, 4), b512, 0, stream>>>(
        h2, 128, Wt + 65536, 128, b1, uB, 512, 128, nullptr, 0, n, nullptr, nullptr, nullptr);
    // FFN2: u @ W2 + b2 + x2 -> d_out (K=512 -> 4 k-tiles)
    gemm_lds<false, false, false, 4><<<dim3(rb, 1), b512, 0, stream>>>(
        uB, 512, Wt + 131072, 512, b2, out, 128, 0, out, 128, n, nullptr, nullptr, nullptr);
}